// Round 2
// baseline (2088.533 us; speedup 1.0000x reference)
//
#include <hip/hip_runtime.h>
#include <hip/hip_bf16.h>

// ---------------------------------------------------------------------------
// PCELayer: router(softmax over fourier feats) + 8 expert conv3x3+GN+SiLU+res,
// weighted merge, merge GN+SiLU gamma-residual, post conv3x3+GN+SiLU.
// Convs run as implicit GEMM on bf16 MFMA. Per-block: 256 pixels x 128 cout,
// LDS holds 4 input rows (160px) + all 9 taps of B per 32-cin chunk ->
// 1152 MFMAs per barrier pair.
// ---------------------------------------------------------------------------

typedef __attribute__((ext_vector_type(8))) short bf16x8;
typedef __attribute__((ext_vector_type(4))) float f32x4;
typedef __attribute__((ext_vector_type(8))) unsigned short u16x8;
typedef __attribute__((ext_vector_type(4))) unsigned short u16x4;

__device__ __forceinline__ float b2f(unsigned short u) {
  unsigned int v = ((unsigned int)u) << 16;
  return __builtin_bit_cast(float, v);
}
__device__ __forceinline__ unsigned short f2b(float f) {
  __hip_bfloat16 h = __float2bfloat16(f);
  return __builtin_bit_cast(unsigned short, h);
}
__device__ __forceinline__ float silu_f(float x) {
  return x / (1.f + __expf(-x));
}
__device__ __forceinline__ void gll16(const void* g, void* l) {
  __builtin_amdgcn_global_load_lds(
      (const __attribute__((address_space(1))) unsigned int*)g,
      (__attribute__((address_space(3))) unsigned int*)l, 16, 0, 0);
}

// ---- router: 64 patches x 8 experts -------------------------------------
__global__ void k_router(const float* __restrict__ rw, const float* __restrict__ rb,
                         float* __restrict__ wts) {
  int t = threadIdx.x;
  if (t >= 64) return;
  int py = t >> 3, px = t & 7;
  float cy = (py + 0.5f) / 8.f, cx = (px + 0.5f) / 8.f;
  const float PI = 3.14159265358979323846f;
  float f[16];
#pragma unroll
  for (int k = 0; k < 4; ++k) {
    float fr = (float)(1 << k) * PI;
    f[k]      = sinf(cy * fr);
    f[4 + k]  = cosf(cy * fr);
    f[8 + k]  = sinf(cx * fr);
    f[12 + k] = cosf(cx * fr);
  }
  float lg[8], mx = -1e30f;
#pragma unroll
  for (int e = 0; e < 8; ++e) {
    float a = rb[e];
#pragma unroll
    for (int k = 0; k < 16; ++k) a += f[k] * rw[k * 8 + e];
    lg[e] = a; mx = fmaxf(mx, a);
  }
  float s = 0.f;
#pragma unroll
  for (int e = 0; e < 8; ++e) { lg[e] = __expf(lg[e] - mx); s += lg[e]; }
  float inv = 1.f / s;
#pragma unroll
  for (int e = 0; e < 8; ++e) wts[t * 8 + e] = lg[e] * inv;
}

// ---- x (NCHW f32) -> padded NHWC bf16 [8][130][130][128] ------------------
__global__ void k_build_xpad(const float* __restrict__ x, __hip_bfloat16* __restrict__ xp) {
  int bx = blockIdx.x;
  int wb = bx & 1, cib = (bx >> 1) & 1;
  int h = (bx >> 2) & 127, b = bx >> 9;
  int w0 = wb * 64, ci0 = cib * 64;
  __shared__ float t[64][65];
  int tid = threadIdx.x;
#pragma unroll
  for (int r = 0; r < 16; ++r) {
    int idx = r * 256 + tid;
    int i = idx >> 6, j = idx & 63;  // i: ci, j: w
    t[i][j] = x[(((size_t)b * 128 + ci0 + i) * 128 + h) * 128 + w0 + j];
  }
  __syncthreads();
  unsigned short* xpu = (unsigned short*)xp;
#pragma unroll
  for (int r = 0; r < 16; ++r) {
    int idx = r * 256 + tid;
    int j = idx >> 6, i = idx & 63;  // j: w, i: ci
    xpu[(((size_t)b * 130 + h + 1) * 130 + (w0 + j + 1)) * 128 + ci0 + i] = f2b(t[i][j]);
  }
}

// ---- weights [e][co][ci][3][3] f32 -> [e][tap][co][ci] bf16 ---------------
__global__ void k_build_w(const float* __restrict__ src, __hip_bfloat16* __restrict__ dst,
                          int total) {
  int o = blockIdx.x * 256 + threadIdx.x;
  if (o >= total) return;
  int ci = o & 127, co = (o >> 7) & 127;
  int r = o >> 14; int tp = r % 9, e = r / 9;
  ((unsigned short*)dst)[o] =
      f2b(src[(((size_t)e * 128 + co) * 128 + ci) * 9 + tp]);
}

// ---- conv3x3 implicit GEMM: 256 pixels (2 rows) x 128 cout per block ------
// LDS: A = [4 rows][160 px][32 cin] (41KB), B = [9 taps][128 co][32 cin] (72KB)
// single-buffered; 4 stages (cin chunks); 1152 MFMAs per barrier pair.
__global__ __launch_bounds__(512, 2) void k_conv(
    const unsigned short* __restrict__ xpu, const unsigned short* __restrict__ wtu,
    unsigned short* __restrict__ outu, float* __restrict__ stats) {
  __shared__ __align__(16) char smem[114688];
  char* Al = smem;            // 40960 B
  char* Bl = smem + 40960;    // 73728 B
  const int bx = blockIdx.x;
  const int b = bx >> 6;
  const int h0 = (bx & 63) << 1;
  const int tid = threadIdx.x;
  const int lane = tid & 63;
  const int wid = tid >> 6;          // 0..7
  const int wm = wid >> 1, wn = wid & 1;
  const int rl = lane & 15, kg = lane >> 4;

  // precompute LDS read byte-offsets (cin-chunk invariant)
  int aoff[3][3][4];  // [ky][kx][mb]
  int boff[9][4];     // [tap][nb]
#pragma unroll
  for (int mb = 0; mb < 4; ++mb) {
    int m = wm * 64 + mb * 16 + rl;
    int ro = m >> 7, w = m & 127;
#pragma unroll
    for (int ky = 0; ky < 3; ++ky)
#pragma unroll
      for (int kx = 0; kx < 3; ++kx) {
        int px = w + kx;
        aoff[ky][kx][mb] = (((ro + ky) * 160 + px) * 4 + (kg ^ ((px >> 1) & 3))) * 16;
      }
  }
#pragma unroll
  for (int t = 0; t < 9; ++t)
#pragma unroll
    for (int nb = 0; nb < 4; ++nb) {
      int co = wn * 64 + nb * 16 + rl;
      boff[t][nb] = ((t * 128 + co) * 4 + (kg ^ ((co >> 1) & 3))) * 16;
    }

  f32x4 acc[4][4] = {};  // [mb][nb]; D rows = cout (operands swapped)

#pragma unroll
  for (int cc = 0; cc < 4; ++cc) {
    __syncthreads();
    // stage A: 4 rows x 160 px x 32 cin = 2560 x 16B slots (5 per thread)
#pragma unroll
    for (int it = 0; it < 5; ++it) {
      int s = it * 512 + tid;
      int r = s / 640;
      int rem = s - r * 640;
      int px = rem >> 2, q = rem & 3;
      int qg = q ^ ((px >> 1) & 3);
      gll16(xpu + ((size_t)((b * 130 + h0 + r) * 130 + px)) * 128 + cc * 32 + qg * 8,
            Al + s * 16);
    }
    // stage B: 9 taps x 128 co x 32 cin = 4608 x 16B slots (9 per thread)
#pragma unroll
    for (int it = 0; it < 9; ++it) {
      int s = it * 512 + tid;
      int t = s >> 9;
      int rem = s & 511;
      int co = rem >> 2, q = rem & 3;
      int qg = q ^ ((co >> 1) & 3);
      gll16(wtu + ((size_t)(t * 128 + co)) * 128 + cc * 32 + qg * 8, Bl + s * 16);
    }
    __syncthreads();
#pragma unroll
    for (int ky = 0; ky < 3; ++ky)
#pragma unroll
      for (int kx = 0; kx < 3; ++kx) {
        const int t = ky * 3 + kx;
        bf16x8 aF[4], bF[4];
#pragma unroll
        for (int mb = 0; mb < 4; ++mb) aF[mb] = *(const bf16x8*)(Al + aoff[ky][kx][mb]);
#pragma unroll
        for (int nb = 0; nb < 4; ++nb) bF[nb] = *(const bf16x8*)(Bl + boff[t][nb]);
#pragma unroll
        for (int mb = 0; mb < 4; ++mb)
#pragma unroll
          for (int nb = 0; nb < 4; ++nb)
            acc[mb][nb] = __builtin_amdgcn_mfma_f32_16x16x32_bf16(
                bF[nb], aF[mb], acc[mb][nb], 0, 0, 0);
      }
  }

  // epilogue: lane holds 4 consecutive cout per frag -> 8B packed stores
  float sv[4] = {0, 0, 0, 0}, qv[4] = {0, 0, 0, 0};
#pragma unroll
  for (int mb = 0; mb < 4; ++mb) {
    int m = wm * 64 + mb * 16 + rl;
    int hh = h0 + (m >> 7), w = m & 127;
    size_t base = (((size_t)b * 128 + hh) * 128 + w) * 128;
#pragma unroll
    for (int nb = 0; nb < 4; ++nb) {
      int co0 = wn * 64 + nb * 16 + kg * 4;
      u16x4 pk;
#pragma unroll
      for (int j = 0; j < 4; ++j) {
        float v = acc[mb][nb][j];
        pk[j] = f2b(v);
        sv[nb] += v; qv[nb] += v * v;
      }
      *(u16x4*)(outu + base + co0) = pk;
    }
  }
#pragma unroll
  for (int nb = 0; nb < 4; ++nb) {
    float a = sv[nb], q = qv[nb];
#pragma unroll
    for (int o = 32; o > 0; o >>= 1) { a += __shfl_down(a, o); q += __shfl_down(q, o); }
    if (lane == 0) {
      int g = wn * 4 + nb;
      atomicAdd(&stats[(b * 8 + g) * 2 + 0], a);
      atomicAdd(&stats[(b * 8 + g) * 2 + 1], q);
    }
  }
}

// ---- merge NEXP experts: merged (+)= sum_e w_e*silu(gn_e(conv_e)) ---------
// flags: bit0 = accumulate into merged; bit1 = last pass (add x, merge-GN stats)
template <int NEXP>
__global__ void k_merge(const unsigned short* __restrict__ c0,
                        const unsigned short* __restrict__ c1,
                        const unsigned short* __restrict__ c2,
                        const unsigned short* __restrict__ c3,
                        const float* __restrict__ st, const float* __restrict__ eg,
                        const float* __restrict__ eb, const float* __restrict__ wts,
                        unsigned short* __restrict__ merged,
                        const unsigned short* __restrict__ xp,
                        float* __restrict__ st2, int e0, int flags) {
  __shared__ float sg[16];
  int tid = threadIdx.x;
  if (tid < 16) sg[tid] = 0.f;
  __syncthreads();
  size_t idx = ((size_t)blockIdx.x * 256 + tid) * 8;
  int co0 = (int)(idx & 127);
  size_t pix = idx >> 7;
  int w = (int)(pix & 127), h = (int)((pix >> 7) & 127), b = (int)(pix >> 14);
  int g = co0 >> 4;
  const float cnt = 16.f * 128.f * 128.f;
  int patch = (h >> 4) * 8 + (w >> 4);
  const unsigned short* cs[4] = {c0, c1, c2, c3};
  float a[8] = {0, 0, 0, 0, 0, 0, 0, 0};
#pragma unroll
  for (int k = 0; k < NEXP; ++k) {
    int e = e0 + k;
    float mean = st[e * 128 + (b * 8 + g) * 2] / cnt;
    float var = st[e * 128 + (b * 8 + g) * 2 + 1] / cnt - mean * mean;
    float rstd = rsqrtf(var + 1e-5f);
    float we = wts[patch * 8 + e];
    u16x8 cv = *(const u16x8*)(cs[k] + idx);
#pragma unroll
    for (int i = 0; i < 8; ++i) {
      float xn = (b2f(cv[i]) - mean) * rstd * eg[e * 128 + co0 + i] + eb[e * 128 + co0 + i];
      a[i] += we * silu_f(xn);
    }
  }
  if (flags & 1) {
    u16x8 mv = *(const u16x8*)(merged + idx);
#pragma unroll
    for (int i = 0; i < 8; ++i) a[i] += b2f(mv[i]);
  }
  u16x8 out;
  float s = 0.f, q = 0.f;
  if (flags & 2) {
    const unsigned short* xr =
        xp + (((size_t)b * 130 + h + 1) * 130 + (w + 1)) * 128 + co0;
    u16x8 xv = *(const u16x8*)xr;
#pragma unroll
    for (int i = 0; i < 8; ++i) {
      a[i] += b2f(xv[i]);
      out[i] = f2b(a[i]);
      float rv = b2f(out[i]);
      s += rv; q += rv * rv;
    }
  } else {
#pragma unroll
    for (int i = 0; i < 8; ++i) out[i] = f2b(a[i]);
  }
  *(u16x8*)(merged + idx) = out;
  if (flags & 2) {
    atomicAdd(&sg[g * 2 + 0], s);
    atomicAdd(&sg[g * 2 + 1], q);
    __syncthreads();
    if (tid < 16) atomicAdd(&st2[(b * 8 + (tid >> 1)) * 2 + (tid & 1)], sg[tid]);
  }
}

// ---- y = x + gamma*silu(gn(M)); write bf16 y into padded buffer (in place) -
__global__ void k_ypass(const unsigned short* __restrict__ merged,
                        unsigned short* __restrict__ xp,
                        const float* __restrict__ st, const float* __restrict__ mg,
                        const float* __restrict__ mbv, const float* __restrict__ gptr) {
  size_t idx = ((size_t)blockIdx.x * 256 + threadIdx.x) * 8;
  int co0 = (int)(idx & 127);
  size_t pix = idx >> 7;
  int w = (int)(pix & 127), h = (int)((pix >> 7) & 127), b = (int)(pix >> 14);
  int g = co0 >> 4;
  const float cnt = 16.f * 128.f * 128.f;
  float mean = st[(b * 8 + g) * 2] / cnt;
  float var = st[(b * 8 + g) * 2 + 1] / cnt - mean * mean;
  float rstd = rsqrtf(var + 1e-5f);
  float gm = gptr[0];
  unsigned short* xr = xp + (((size_t)b * 130 + h + 1) * 130 + (w + 1)) * 128 + co0;
  u16x8 xv = *(const u16x8*)xr;
  u16x8 mv = *(const u16x8*)(merged + idx);
  u16x8 yv;
#pragma unroll
  for (int i = 0; i < 8; ++i) {
    float xf = b2f(xv[i]);
    float M = b2f(mv[i]);
    float xn = (M - mean) * rstd * mg[co0 + i] + mbv[co0 + i];
    yv[i] = f2b(xf + gm * silu_f(xn));
  }
  *(u16x8*)xr = yv;
}

// ---- final: out = silu(gn3(conv3)), NHWC bf16 -> NCHW f32 via LDS transpose
__global__ void k_final(const __hip_bfloat16* __restrict__ conv, const float* __restrict__ st,
                        const float* __restrict__ pg, const float* __restrict__ pb,
                        float* __restrict__ out) {
  int bx = blockIdx.x;
  int wb = bx & 1, h = (bx >> 1) & 127, b = bx >> 8;
  int w0 = wb * 64;
  __shared__ float t[64][129];
  int tid = threadIdx.x;
  const float cnt = 16.f * 128.f * 128.f;
  const unsigned short* cu = (const unsigned short*)conv;
#pragma unroll
  for (int r = 0; r < 32; ++r) {
    int e2 = r * 256 + tid;
    int co = e2 & 127, wl = e2 >> 7;
    int g = co >> 4;
    float mean = st[(b * 8 + g) * 2] / cnt;
    float var = st[(b * 8 + g) * 2 + 1] / cnt - mean * mean;
    float rstd = rsqrtf(var + 1e-5f);
    float v = b2f(cu[(((size_t)b * 128 + h) * 128 + w0 + wl) * 128 + co]);
    float xn = (v - mean) * rstd * pg[co] + pb[co];
    t[wl][co] = silu_f(xn);
  }
  __syncthreads();
#pragma unroll
  for (int r = 0; r < 8; ++r) {
    int f = r * 256 + tid;
    int jb = f & 15, co = f >> 4;
    f32x4 o;
#pragma unroll
    for (int j = 0; j < 4; ++j) o[j] = t[jb * 4 + j][co];
    *(f32x4*)&out[(((size_t)b * 128 + co) * 128 + h) * 128 + w0 + jb * 4] = o;
  }
}

// ---------------------------------------------------------------------------
extern "C" void kernel_launch(void* const* d_in, const int* in_sizes, int n_in,
                              void* d_out, int out_size, void* d_ws, size_t ws_size,
                              hipStream_t stream) {
  const float* x        = (const float*)d_in[0];
  const float* expert_w = (const float*)d_in[1];
  const float* expert_g = (const float*)d_in[2];
  const float* expert_b = (const float*)d_in[3];
  const float* router_w = (const float*)d_in[4];
  const float* router_b = (const float*)d_in[5];
  const float* merge_g  = (const float*)d_in[6];
  const float* merge_b  = (const float*)d_in[7];
  const float* gamma    = (const float*)d_in[8];
  const float* post_w   = (const float*)d_in[9];
  const float* post_g   = (const float*)d_in[10];
  const float* post_b   = (const float*)d_in[11];

  char* ws = (char*)d_ws;
  float* wts           = (float*)(ws + 0);                 // 2048 B
  float* stats         = (float*)(ws + 2048);              // 5120 B (10 x 128 f32)
  unsigned short* wtb  = (unsigned short*)(ws + 8192);     // 2,654,208 B
  unsigned short* xpad = (unsigned short*)(ws + 2662400);  // 34,611,200 B
  // conv output buffers + merged (bf16, 33,554,432 B each)
  const size_t NEED2 = 137936896ull;   // 2 conv bufs
  const size_t NEED4 = 205045760ull;   // 4 conv bufs
  int nbuf = (ws_size >= NEED4) ? 4 : 2;
  unsigned short* bufs[4];
  unsigned short* merged;
  bufs[0] = (unsigned short*)(ws + 37273600ull);
  bufs[1] = (unsigned short*)(ws + 70828032ull);
  if (nbuf == 4) {
    bufs[2] = (unsigned short*)(ws + 104382464ull);
    bufs[3] = (unsigned short*)(ws + 137936896ull);
    merged  = (unsigned short*)(ws + 171491328ull);
  } else {
    bufs[2] = bufs[0]; bufs[3] = bufs[1];
    merged  = (unsigned short*)(ws + 104382464ull);
  }
  if (ws_size < NEED2) {  // graceful fallback, no corruption
    hipMemsetAsync(d_out, 0, (size_t)out_size * 4, stream);
    return;
  }

  hipMemsetAsync(stats, 0, 5120, stream);
  hipMemsetAsync(xpad, 0, 34611200ull, stream);
  k_router<<<1, 64, 0, stream>>>(router_w, router_b, wts);
  k_build_xpad<<<4096, 256, 0, stream>>>(x, (__hip_bfloat16*)xpad);
  k_build_w<<<4608, 256, 0, stream>>>(expert_w, (__hip_bfloat16*)wtb, 1179648);
  k_build_w<<<576, 256, 0, stream>>>(post_w, (__hip_bfloat16*)(wtb + 1179648), 147456);

  if (nbuf == 4) {
    for (int p = 0; p < 2; ++p) {
      for (int k = 0; k < 4; ++k) {
        int e = p * 4 + k;
        k_conv<<<512, 512, 0, stream>>>(xpad, wtb + (size_t)e * 147456, bufs[k],
                                        stats + e * 128);
      }
      int flags = (p > 0 ? 1 : 0) | (p == 1 ? 2 : 0);
      k_merge<4><<<8192, 256, 0, stream>>>(bufs[0], bufs[1], bufs[2], bufs[3], stats,
                                           expert_g, expert_b, wts, merged, xpad,
                                           stats + 8 * 128, p * 4, flags);
    }
  } else {
    for (int p = 0; p < 4; ++p) {
      for (int k = 0; k < 2; ++k) {
        int e = p * 2 + k;
        k_conv<<<512, 512, 0, stream>>>(xpad, wtb + (size_t)e * 147456, bufs[k],
                                        stats + e * 128);
      }
      int flags = (p > 0 ? 1 : 0) | (p == 3 ? 2 : 0);
      k_merge<2><<<8192, 256, 0, stream>>>(bufs[0], bufs[1], bufs[0], bufs[1], stats,
                                           expert_g, expert_b, wts, merged, xpad,
                                           stats + 8 * 128, p * 2, flags);
    }
  }
  k_ypass<<<8192, 256, 0, stream>>>(merged, xpad, stats + 8 * 128, merge_g, merge_b, gamma);
  k_conv<<<512, 512, 0, stream>>>(xpad, wtb + 1179648ull, bufs[0], stats + 9 * 128);
  k_final<<<2048, 256, 0, stream>>>((const __hip_bfloat16*)bufs[0], stats + 9 * 128,
                                    post_g, post_b, (float*)d_out);
}

// Round 3
// 1443.477 us; speedup vs baseline: 1.4469x; 1.4469x over previous
//
#include <hip/hip_runtime.h>
#include <hip/hip_bf16.h>

// ---------------------------------------------------------------------------
// PCELayer. Convs as implicit GEMM on bf16 MFMA.
// R3 structure: k_conv = 4 waves/block, 34.8KB LDS -> 4 blocks/CU (TLP hides
// the stage-drain); 12 stages of (32cin x 3taps); per-block partial GN stats
// (no global atomics) + tiny reduction kernels.
// ---------------------------------------------------------------------------

typedef __attribute__((ext_vector_type(8))) short bf16x8;
typedef __attribute__((ext_vector_type(4))) float f32x4;
typedef __attribute__((ext_vector_type(8))) unsigned short u16x8;
typedef __attribute__((ext_vector_type(4))) unsigned short u16x4;

__device__ __forceinline__ float b2f(unsigned short u) {
  unsigned int v = ((unsigned int)u) << 16;
  return __builtin_bit_cast(float, v);
}
__device__ __forceinline__ unsigned short f2b(float f) {
  __hip_bfloat16 h = __float2bfloat16(f);
  return __builtin_bit_cast(unsigned short, h);
}
__device__ __forceinline__ float silu_f(float x) {
  return x / (1.f + __expf(-x));
}
__device__ __forceinline__ void gll16(const void* g, void* l) {
  __builtin_amdgcn_global_load_lds(
      (const __attribute__((address_space(1))) unsigned int*)g,
      (__attribute__((address_space(3))) unsigned int*)l, 16, 0, 0);
}

// ---- router: 64 patches x 8 experts -------------------------------------
__global__ void k_router(const float* __restrict__ rw, const float* __restrict__ rb,
                         float* __restrict__ wts) {
  int t = threadIdx.x;
  if (t >= 64) return;
  int py = t >> 3, px = t & 7;
  float cy = (py + 0.5f) / 8.f, cx = (px + 0.5f) / 8.f;
  const float PI = 3.14159265358979323846f;
  float f[16];
#pragma unroll
  for (int k = 0; k < 4; ++k) {
    float fr = (float)(1 << k) * PI;
    f[k]      = sinf(cy * fr);
    f[4 + k]  = cosf(cy * fr);
    f[8 + k]  = sinf(cx * fr);
    f[12 + k] = cosf(cx * fr);
  }
  float lg[8], mx = -1e30f;
#pragma unroll
  for (int e = 0; e < 8; ++e) {
    float a = rb[e];
#pragma unroll
    for (int k = 0; k < 16; ++k) a += f[k] * rw[k * 8 + e];
    lg[e] = a; mx = fmaxf(mx, a);
  }
  float s = 0.f;
#pragma unroll
  for (int e = 0; e < 8; ++e) { lg[e] = __expf(lg[e] - mx); s += lg[e]; }
  float inv = 1.f / s;
#pragma unroll
  for (int e = 0; e < 8; ++e) wts[t * 8 + e] = lg[e] * inv;
}

// ---- x (NCHW f32) -> padded NHWC bf16 [8][130][130][128] ------------------
__global__ void k_build_xpad(const float* __restrict__ x, __hip_bfloat16* __restrict__ xp) {
  int bx = blockIdx.x;
  int wb = bx & 1, cib = (bx >> 1) & 1;
  int h = (bx >> 2) & 127, b = bx >> 9;
  int w0 = wb * 64, ci0 = cib * 64;
  __shared__ float t[64][65];
  int tid = threadIdx.x;
#pragma unroll
  for (int r = 0; r < 16; ++r) {
    int idx = r * 256 + tid;
    int i = idx >> 6, j = idx & 63;  // i: ci, j: w
    t[i][j] = x[(((size_t)b * 128 + ci0 + i) * 128 + h) * 128 + w0 + j];
  }
  __syncthreads();
  unsigned short* xpu = (unsigned short*)xp;
#pragma unroll
  for (int r = 0; r < 16; ++r) {
    int idx = r * 256 + tid;
    int j = idx >> 6, i = idx & 63;  // j: w, i: ci
    xpu[(((size_t)b * 130 + h + 1) * 130 + (w0 + j + 1)) * 128 + ci0 + i] = f2b(t[i][j]);
  }
}

// ---- weights [e][co][ci][3][3] f32 -> [e][tap][co][ci] bf16 ---------------
__global__ void k_build_w(const float* __restrict__ src, __hip_bfloat16* __restrict__ dst,
                          int total) {
  int o = blockIdx.x * 256 + threadIdx.x;
  if (o >= total) return;
  int ci = o & 127, co = (o >> 7) & 127;
  int r = o >> 14; int tp = r % 9, e = r / 9;
  ((unsigned short*)dst)[o] =
      f2b(src[(((size_t)e * 128 + co) * 128 + ci) * 9 + tp]);
}

// ---- conv3x3 implicit GEMM: 128 pixels (1 row) x 128 cout per block -------
// 4 waves, LDS 34816 B -> 4 blocks/CU. 12 stages = 4 cin-chunks x 3 ky.
// Per stage: A = 1 row x 160px x 32ci (10240 B), B = 3 taps x 128co x 32ci
// (24576 B); 48 MFMA/wave per stage. GN partials per block (no atomics).
__global__ __launch_bounds__(256, 4) void k_conv(
    const unsigned short* __restrict__ xpu, const unsigned short* __restrict__ wtu,
    unsigned short* __restrict__ outu, float* __restrict__ partials) {
  __shared__ __align__(16) char smem[34816];
  char* Al = smem;          // 10240 B
  char* Bl = smem + 10240;  // 24576 B
  const int bx = blockIdx.x;
  const int b = bx >> 7, h0 = bx & 127;
  const int tid = threadIdx.x;
  const int lane = tid & 63, wid = tid >> 6;
  const int wm = wid >> 1, wn = wid & 1;
  const int rl = lane & 15, kg = lane >> 4;

  // LDS read byte-offsets (stage-invariant)
  int aoff[3][4];  // [kx][mb]
  int boff[3][4];  // [kx][nb]
#pragma unroll
  for (int mb = 0; mb < 4; ++mb) {
    int w = wm * 64 + mb * 16 + rl;
#pragma unroll
    for (int kx = 0; kx < 3; ++kx) {
      int px = w + kx;
      aoff[kx][mb] = (px * 4 + (kg ^ ((px >> 1) & 3))) * 16;
    }
  }
#pragma unroll
  for (int kx = 0; kx < 3; ++kx)
#pragma unroll
    for (int nb = 0; nb < 4; ++nb) {
      int co = wn * 64 + nb * 16 + rl;
      boff[kx][nb] = ((kx * 128 + co) * 4 + (kg ^ ((co >> 1) & 3))) * 16;
    }

  f32x4 acc[4][4] = {};  // [mb][nb]; operands swapped: lane holds 4 cout

#pragma unroll
  for (int cc = 0; cc < 4; ++cc) {
#pragma unroll
    for (int ky = 0; ky < 3; ++ky) {
      __syncthreads();
      // stage A: row h0+ky (padded coords), 160 px x 32 ci = 640 slots
      {
        const size_t arow = (size_t)(b * 130 + h0 + ky) * 130;
#pragma unroll
        for (int it = 0; it < 3; ++it) {
          int s = it * 256 + tid;
          if (it < 2 || tid < 128) {  // wave-granular tail (waves 0,1 full)
            int px = s >> 2, q = s & 3;
            int qg = q ^ ((px >> 1) & 3);
            gll16(xpu + (arow + px) * 128 + cc * 32 + qg * 8, Al + s * 16);
          }
        }
      }
      // stage B: taps ky*3..ky*3+2, 128 co x 32 ci each = 1536 slots
#pragma unroll
      for (int it = 0; it < 6; ++it) {
        int s = it * 256 + tid;
        int t3 = s >> 9, rem = s & 511;
        int co = rem >> 2, q = rem & 3;
        int qg = q ^ ((co >> 1) & 3);
        gll16(wtu + ((size_t)((ky * 3 + t3) * 128 + co)) * 128 + cc * 32 + qg * 8,
              Bl + s * 16);
      }
      __syncthreads();
#pragma unroll
      for (int kx = 0; kx < 3; ++kx) {
        bf16x8 aF[4], bF[4];
#pragma unroll
        for (int mb = 0; mb < 4; ++mb) aF[mb] = *(const bf16x8*)(Al + aoff[kx][mb]);
#pragma unroll
        for (int nb = 0; nb < 4; ++nb) bF[nb] = *(const bf16x8*)(Bl + boff[kx][nb]);
#pragma unroll
        for (int mb = 0; mb < 4; ++mb)
#pragma unroll
          for (int nb = 0; nb < 4; ++nb)
            acc[mb][nb] = __builtin_amdgcn_mfma_f32_16x16x32_bf16(
                bF[nb], aF[mb], acc[mb][nb], 0, 0, 0);
      }
    }
  }

  // epilogue: packed 8B stores + per-block GN partials via LDS reduce
  float sv[4] = {0, 0, 0, 0}, qv[4] = {0, 0, 0, 0};
#pragma unroll
  for (int mb = 0; mb < 4; ++mb) {
    int w = wm * 64 + mb * 16 + rl;
    size_t base = (((size_t)b * 128 + h0) * 128 + w) * 128;
#pragma unroll
    for (int nb = 0; nb < 4; ++nb) {
      int co0 = wn * 64 + nb * 16 + kg * 4;
      u16x4 pk;
#pragma unroll
      for (int j = 0; j < 4; ++j) {
        float v = acc[mb][nb][j];
        pk[j] = f2b(v);
        sv[nb] += v; qv[nb] += v * v;
      }
      *(u16x4*)(outu + base + co0) = pk;
    }
  }
  __syncthreads();
  float* sg = (float*)smem;
  if (tid < 16) sg[tid] = 0.f;
  __syncthreads();
#pragma unroll
  for (int nb = 0; nb < 4; ++nb) {
    float a = sv[nb], q = qv[nb];
#pragma unroll
    for (int o = 32; o > 0; o >>= 1) { a += __shfl_down(a, o); q += __shfl_down(q, o); }
    if (lane == 0) {
      int g = wn * 4 + nb;
      atomicAdd(&sg[g * 2 + 0], a);   // LDS atomics: 8 waves->16 slots, cheap
      atomicAdd(&sg[g * 2 + 1], q);
    }
  }
  __syncthreads();
  if (tid < 16) partials[(size_t)bx * 16 + tid] = sg[tid];
}

// ---- reduce per-block partials -> stats[b*16+slot] ------------------------
// partials[(b*nper + i)*16 + slot]; grid 1 x 512 threads.
__global__ void k_redstats(const float* __restrict__ partials, float* __restrict__ stats,
                           int nper) {
  int t = threadIdx.x;
  int o = t >> 2, j = t & 3;  // o: 0..127
  int b = o >> 4, slot = o & 15;
  int chunk = nper >> 2;
  float s = 0.f;
  for (int i = j * chunk; i < (j + 1) * chunk; ++i)
    s += partials[((size_t)b * nper + i) * 16 + slot];
  s += __shfl_xor(s, 1);
  s += __shfl_xor(s, 2);
  if (j == 0) stats[o] = s;
}

// ---- merge NEXP experts: merged (+)= sum_e w_e*silu(gn_e(conv_e)) ---------
// flags: bit0 = accumulate; bit1 = last pass (add x, write merge-GN partials)
template <int NEXP>
__global__ void k_merge(const unsigned short* __restrict__ c0,
                        const unsigned short* __restrict__ c1,
                        const unsigned short* __restrict__ c2,
                        const unsigned short* __restrict__ c3,
                        const float* __restrict__ st, const float* __restrict__ eg,
                        const float* __restrict__ eb, const float* __restrict__ wts,
                        unsigned short* __restrict__ merged,
                        const unsigned short* __restrict__ xp,
                        float* __restrict__ partials2, int e0, int flags) {
  __shared__ float sg[16];
  int tid = threadIdx.x;
  if (tid < 16) sg[tid] = 0.f;
  __syncthreads();
  size_t idx = ((size_t)blockIdx.x * 256 + tid) * 8;
  int co0 = (int)(idx & 127);
  size_t pix = idx >> 7;
  int w = (int)(pix & 127), h = (int)((pix >> 7) & 127), b = (int)(pix >> 14);
  int g = co0 >> 4;
  const float cnt = 16.f * 128.f * 128.f;
  int patch = (h >> 4) * 8 + (w >> 4);
  const unsigned short* cs[4] = {c0, c1, c2, c3};
  float a[8] = {0, 0, 0, 0, 0, 0, 0, 0};
#pragma unroll
  for (int k = 0; k < NEXP; ++k) {
    int e = e0 + k;
    float mean = st[e * 128 + (b * 8 + g) * 2] / cnt;
    float var = st[e * 128 + (b * 8 + g) * 2 + 1] / cnt - mean * mean;
    float rstd = rsqrtf(var + 1e-5f);
    float we = wts[patch * 8 + e];
    u16x8 cv = *(const u16x8*)(cs[k] + idx);
#pragma unroll
    for (int i = 0; i < 8; ++i) {
      float xn = (b2f(cv[i]) - mean) * rstd * eg[e * 128 + co0 + i] + eb[e * 128 + co0 + i];
      a[i] += we * silu_f(xn);
    }
  }
  if (flags & 1) {
    u16x8 mv = *(const u16x8*)(merged + idx);
#pragma unroll
    for (int i = 0; i < 8; ++i) a[i] += b2f(mv[i]);
  }
  u16x8 out;
  float s = 0.f, q = 0.f;
  if (flags & 2) {
    const unsigned short* xr =
        xp + (((size_t)b * 130 + h + 1) * 130 + (w + 1)) * 128 + co0;
    u16x8 xv = *(const u16x8*)xr;
#pragma unroll
    for (int i = 0; i < 8; ++i) {
      a[i] += b2f(xv[i]);
      out[i] = f2b(a[i]);
      float rv = b2f(out[i]);
      s += rv; q += rv * rv;
    }
  } else {
#pragma unroll
    for (int i = 0; i < 8; ++i) out[i] = f2b(a[i]);
  }
  *(u16x8*)(merged + idx) = out;
  if (flags & 2) {
    atomicAdd(&sg[g * 2 + 0], s);
    atomicAdd(&sg[g * 2 + 1], q);
    __syncthreads();
    if (tid < 16) partials2[(size_t)blockIdx.x * 16 + tid] = sg[tid];
  }
}

// ---- y = x + gamma*silu(gn(M)); write bf16 y into padded buffer (in place) -
__global__ void k_ypass(const unsigned short* __restrict__ merged,
                        unsigned short* __restrict__ xp,
                        const float* __restrict__ st, const float* __restrict__ mg,
                        const float* __restrict__ mbv, const float* __restrict__ gptr) {
  size_t idx = ((size_t)blockIdx.x * 256 + threadIdx.x) * 8;
  int co0 = (int)(idx & 127);
  size_t pix = idx >> 7;
  int w = (int)(pix & 127), h = (int)((pix >> 7) & 127), b = (int)(pix >> 14);
  int g = co0 >> 4;
  const float cnt = 16.f * 128.f * 128.f;
  float mean = st[(b * 8 + g) * 2] / cnt;
  float var = st[(b * 8 + g) * 2 + 1] / cnt - mean * mean;
  float rstd = rsqrtf(var + 1e-5f);
  float gm = gptr[0];
  unsigned short* xr = xp + (((size_t)b * 130 + h + 1) * 130 + (w + 1)) * 128 + co0;
  u16x8 xv = *(const u16x8*)xr;
  u16x8 mv = *(const u16x8*)(merged + idx);
  u16x8 yv;
#pragma unroll
  for (int i = 0; i < 8; ++i) {
    float xf = b2f(xv[i]);
    float M = b2f(mv[i]);
    float xn = (M - mean) * rstd * mg[co0 + i] + mbv[co0 + i];
    yv[i] = f2b(xf + gm * silu_f(xn));
  }
  *(u16x8*)xr = yv;
}

// ---- final: out = silu(gn3(conv3)), NHWC bf16 -> NCHW f32 via LDS transpose
__global__ void k_final(const __hip_bfloat16* __restrict__ conv, const float* __restrict__ st,
                        const float* __restrict__ pg, const float* __restrict__ pb,
                        float* __restrict__ out) {
  int bx = blockIdx.x;
  int wb = bx & 1, h = (bx >> 1) & 127, b = bx >> 8;
  int w0 = wb * 64;
  __shared__ float t[64][129];
  int tid = threadIdx.x;
  const float cnt = 16.f * 128.f * 128.f;
  const unsigned short* cu = (const unsigned short*)conv;
#pragma unroll
  for (int r = 0; r < 32; ++r) {
    int e2 = r * 256 + tid;
    int co = e2 & 127, wl = e2 >> 7;
    int g = co >> 4;
    float mean = st[(b * 8 + g) * 2] / cnt;
    float var = st[(b * 8 + g) * 2 + 1] / cnt - mean * mean;
    float rstd = rsqrtf(var + 1e-5f);
    float v = b2f(cu[(((size_t)b * 128 + h) * 128 + w0 + wl) * 128 + co]);
    float xn = (v - mean) * rstd * pg[co] + pb[co];
    t[wl][co] = silu_f(xn);
  }
  __syncthreads();
#pragma unroll
  for (int r = 0; r < 8; ++r) {
    int f = r * 256 + tid;
    int jb = f & 15, co = f >> 4;
    f32x4 o;
#pragma unroll
    for (int j = 0; j < 4; ++j) o[j] = t[jb * 4 + j][co];
    *(f32x4*)&out[(((size_t)b * 128 + co) * 128 + h) * 128 + w0 + jb * 4] = o;
  }
}

// ---------------------------------------------------------------------------
extern "C" void kernel_launch(void* const* d_in, const int* in_sizes, int n_in,
                              void* d_out, int out_size, void* d_ws, size_t ws_size,
                              hipStream_t stream) {
  const float* x        = (const float*)d_in[0];
  const float* expert_w = (const float*)d_in[1];
  const float* expert_g = (const float*)d_in[2];
  const float* expert_b = (const float*)d_in[3];
  const float* router_w = (const float*)d_in[4];
  const float* router_b = (const float*)d_in[5];
  const float* merge_g  = (const float*)d_in[6];
  const float* merge_b  = (const float*)d_in[7];
  const float* gamma    = (const float*)d_in[8];
  const float* post_w   = (const float*)d_in[9];
  const float* post_g   = (const float*)d_in[10];
  const float* post_b   = (const float*)d_in[11];

  char* ws = (char*)d_ws;
  float* wts            = (float*)(ws + 0);          // 2048
  float* stats          = (float*)(ws + 2048);       // 5120 (10 x 128 f32)
  float* partials       = (float*)(ws + 8192);       // 65,536 (1024 x 16)
  float* partials2      = (float*)(ws + 73728);      // 524,288 (8192 x 16)
  unsigned short* wtb   = (unsigned short*)(ws + 598016);    // 2,654,208
  unsigned short* xpad  = (unsigned short*)(ws + 3252224);   // 34,611,200 + 8,192 pad
  unsigned short* bufs[4];
  unsigned short* merged;
  const size_t BUF0 = 37871616ull;
  const size_t NEED2 = BUF0 + 3ull * 33554432ull;  // 138,534,912
  const size_t NEED4 = BUF0 + 5ull * 33554432ull;  // 205,643,776
  int nbuf = (ws_size >= NEED4) ? 4 : 2;
  bufs[0] = (unsigned short*)(ws + BUF0);
  bufs[1] = (unsigned short*)(ws + BUF0 + 33554432ull);
  if (nbuf == 4) {
    bufs[2] = (unsigned short*)(ws + BUF0 + 2ull * 33554432ull);
    bufs[3] = (unsigned short*)(ws + BUF0 + 3ull * 33554432ull);
    merged  = (unsigned short*)(ws + BUF0 + 4ull * 33554432ull);
  } else {
    bufs[2] = bufs[0]; bufs[3] = bufs[1];
    merged  = (unsigned short*)(ws + BUF0 + 2ull * 33554432ull);
  }
  if (ws_size < NEED2) {  // graceful fallback, no corruption
    hipMemsetAsync(d_out, 0, (size_t)out_size * 4, stream);
    return;
  }

  hipMemsetAsync(xpad, 0, 34619392ull, stream);
  k_router<<<1, 64, 0, stream>>>(router_w, router_b, wts);
  k_build_xpad<<<4096, 256, 0, stream>>>(x, (__hip_bfloat16*)xpad);
  k_build_w<<<4608, 256, 0, stream>>>(expert_w, (__hip_bfloat16*)wtb, 1179648);
  k_build_w<<<576, 256, 0, stream>>>(post_w, (__hip_bfloat16*)(wtb + 1179648), 147456);

  if (nbuf == 4) {
    for (int p = 0; p < 2; ++p) {
      for (int k = 0; k < 4; ++k) {
        int e = p * 4 + k;
        k_conv<<<1024, 256, 0, stream>>>(xpad, wtb + (size_t)e * 147456, bufs[k], partials);
        k_redstats<<<1, 512, 0, stream>>>(partials, stats + e * 128, 128);
      }
      int flags = (p > 0 ? 1 : 0) | (p == 1 ? 2 : 0);
      k_merge<4><<<8192, 256, 0, stream>>>(bufs[0], bufs[1], bufs[2], bufs[3], stats,
                                           expert_g, expert_b, wts, merged, xpad,
                                           partials2, p * 4, flags);
    }
  } else {
    for (int p = 0; p < 4; ++p) {
      for (int k = 0; k < 2; ++k) {
        int e = p * 2 + k;
        k_conv<<<1024, 256, 0, stream>>>(xpad, wtb + (size_t)e * 147456, bufs[k], partials);
        k_redstats<<<1, 512, 0, stream>>>(partials, stats + e * 128, 128);
      }
      int flags = (p > 0 ? 1 : 0) | (p == 3 ? 2 : 0);
      k_merge<2><<<8192, 256, 0, stream>>>(bufs[0], bufs[1], bufs[0], bufs[1], stats,
                                           expert_g, expert_b, wts, merged, xpad,
                                           partials2, p * 2, flags);
    }
  }
  k_redstats<<<1, 512, 0, stream>>>(partials2, stats + 8 * 128, 1024);
  k_ypass<<<8192, 256, 0, stream>>>(merged, xpad, stats + 8 * 128, merge_g, merge_b, gamma);
  k_conv<<<1024, 256, 0, stream>>>(xpad, wtb + 1179648ull, bufs[0], partials);
  k_redstats<<<1, 512, 0, stream>>>(partials, stats + 9 * 128, 128);
  k_final<<<2048, 256, 0, stream>>>((const __hip_bfloat16*)bufs[0], stats + 9 * 128,
                                    post_g, post_b, (float*)d_out);
}

// Round 4
// 1322.306 us; speedup vs baseline: 1.5795x; 1.0916x over previous
//
#include <hip/hip_runtime.h>
#include <hip/hip_bf16.h>

// ---------------------------------------------------------------------------
// PCELayer. Convs as implicit GEMM on bf16 MFMA.
// R4: k_conv keeps R3's 4-wave/34.8KB/4-blocks-per-CU structure, adds
// (a) bijective XCD swizzle: XCD k owns image k, rows in order -> B weights
//     and A-halo become L2-resident (FETCH 310MB -> ~40MB);
// (b) LDS-transposed epilogue -> lane-contiguous 1KB/wave stores
//     (WRITE 178MB -> ~34MB);
// (c) grid-parallel stats reductions.
// ---------------------------------------------------------------------------

typedef __attribute__((ext_vector_type(8))) short bf16x8;
typedef __attribute__((ext_vector_type(4))) float f32x4;
typedef __attribute__((ext_vector_type(8))) unsigned short u16x8;
typedef __attribute__((ext_vector_type(4))) unsigned short u16x4;

__device__ __forceinline__ float b2f(unsigned short u) {
  unsigned int v = ((unsigned int)u) << 16;
  return __builtin_bit_cast(float, v);
}
__device__ __forceinline__ unsigned short f2b(float f) {
  __hip_bfloat16 h = __float2bfloat16(f);
  return __builtin_bit_cast(unsigned short, h);
}
__device__ __forceinline__ float silu_f(float x) {
  return x / (1.f + __expf(-x));
}
__device__ __forceinline__ void gll16(const void* g, void* l) {
  __builtin_amdgcn_global_load_lds(
      (const __attribute__((address_space(1))) unsigned int*)g,
      (__attribute__((address_space(3))) unsigned int*)l, 16, 0, 0);
}

// ---- router: 64 patches x 8 experts -------------------------------------
__global__ void k_router(const float* __restrict__ rw, const float* __restrict__ rb,
                         float* __restrict__ wts) {
  int t = threadIdx.x;
  if (t >= 64) return;
  int py = t >> 3, px = t & 7;
  float cy = (py + 0.5f) / 8.f, cx = (px + 0.5f) / 8.f;
  const float PI = 3.14159265358979323846f;
  float f[16];
#pragma unroll
  for (int k = 0; k < 4; ++k) {
    float fr = (float)(1 << k) * PI;
    f[k]      = sinf(cy * fr);
    f[4 + k]  = cosf(cy * fr);
    f[8 + k]  = sinf(cx * fr);
    f[12 + k] = cosf(cx * fr);
  }
  float lg[8], mx = -1e30f;
#pragma unroll
  for (int e = 0; e < 8; ++e) {
    float a = rb[e];
#pragma unroll
    for (int k = 0; k < 16; ++k) a += f[k] * rw[k * 8 + e];
    lg[e] = a; mx = fmaxf(mx, a);
  }
  float s = 0.f;
#pragma unroll
  for (int e = 0; e < 8; ++e) { lg[e] = __expf(lg[e] - mx); s += lg[e]; }
  float inv = 1.f / s;
#pragma unroll
  for (int e = 0; e < 8; ++e) wts[t * 8 + e] = lg[e] * inv;
}

// ---- x (NCHW f32) -> padded NHWC bf16 [8][130][130][128] ------------------
__global__ void k_build_xpad(const float* __restrict__ x, __hip_bfloat16* __restrict__ xp) {
  int bx = blockIdx.x;
  int wb = bx & 1, cib = (bx >> 1) & 1;
  int h = (bx >> 2) & 127, b = bx >> 9;
  int w0 = wb * 64, ci0 = cib * 64;
  __shared__ float t[64][65];
  int tid = threadIdx.x;
#pragma unroll
  for (int r = 0; r < 16; ++r) {
    int idx = r * 256 + tid;
    int i = idx >> 6, j = idx & 63;  // i: ci, j: w
    t[i][j] = x[(((size_t)b * 128 + ci0 + i) * 128 + h) * 128 + w0 + j];
  }
  __syncthreads();
  unsigned short* xpu = (unsigned short*)xp;
#pragma unroll
  for (int r = 0; r < 16; ++r) {
    int idx = r * 256 + tid;
    int j = idx >> 6, i = idx & 63;  // j: w, i: ci
    xpu[(((size_t)b * 130 + h + 1) * 130 + (w0 + j + 1)) * 128 + ci0 + i] = f2b(t[i][j]);
  }
}

// ---- weights [e][co][ci][3][3] f32 -> [e][tap][co][ci] bf16 ---------------
__global__ void k_build_w(const float* __restrict__ src, __hip_bfloat16* __restrict__ dst,
                          int total) {
  int o = blockIdx.x * 256 + threadIdx.x;
  if (o >= total) return;
  int ci = o & 127, co = (o >> 7) & 127;
  int r = o >> 14; int tp = r % 9, e = r / 9;
  ((unsigned short*)dst)[o] =
      f2b(src[(((size_t)e * 128 + co) * 128 + ci) * 9 + tp]);
}

// ---- conv3x3 implicit GEMM: 128 pixels (1 row) x 128 cout per block -------
// 4 waves, LDS 34816 B -> 4 blocks/CU. 12 stages = 4 cin-chunks x 3 ky.
// XCD swizzle: XCD k owns image k, rows in launch order.
__global__ __launch_bounds__(256, 4) void k_conv(
    const unsigned short* __restrict__ xpu, const unsigned short* __restrict__ wtu,
    unsigned short* __restrict__ outu, float* __restrict__ partials) {
  __shared__ __align__(16) char smem[34816];
  char* Al = smem;          // 10240 B
  char* Bl = smem + 10240;  // 24576 B
  const int bx0 = blockIdx.x;
  const int nid = (bx0 & 7) * 128 + (bx0 >> 3);  // bijective XCD remap
  const int b = nid >> 7, h0 = nid & 127;
  const int tid = threadIdx.x;
  const int lane = tid & 63, wid = tid >> 6;
  const int wm = wid >> 1, wn = wid & 1;
  const int rl = lane & 15, kg = lane >> 4;

  // LDS read byte-offsets (stage-invariant)
  int aoff[3][4];  // [kx][mb]
  int boff[3][4];  // [kx][nb]
#pragma unroll
  for (int mb = 0; mb < 4; ++mb) {
    int w = wm * 64 + mb * 16 + rl;
#pragma unroll
    for (int kx = 0; kx < 3; ++kx) {
      int px = w + kx;
      aoff[kx][mb] = (px * 4 + (kg ^ ((px >> 1) & 3))) * 16;
    }
  }
#pragma unroll
  for (int kx = 0; kx < 3; ++kx)
#pragma unroll
    for (int nb = 0; nb < 4; ++nb) {
      int co = wn * 64 + nb * 16 + rl;
      boff[kx][nb] = ((kx * 128 + co) * 4 + (kg ^ ((co >> 1) & 3))) * 16;
    }

  f32x4 acc[4][4] = {};  // [mb][nb]; operands swapped: lane holds 4 cout

#pragma unroll
  for (int cc = 0; cc < 4; ++cc) {
#pragma unroll
    for (int ky = 0; ky < 3; ++ky) {
      __syncthreads();
      // stage A: row h0+ky (padded coords), 160 px x 32 ci = 640 slots
      {
        const size_t arow = (size_t)(b * 130 + h0 + ky) * 130;
#pragma unroll
        for (int it = 0; it < 3; ++it) {
          int s = it * 256 + tid;
          if (it < 2 || tid < 128) {  // wave-granular tail (waves 0,1 full)
            int px = s >> 2, q = s & 3;
            int qg = q ^ ((px >> 1) & 3);
            gll16(xpu + (arow + px) * 128 + cc * 32 + qg * 8, Al + s * 16);
          }
        }
      }
      // stage B: taps ky*3..ky*3+2, 128 co x 32 ci each = 1536 slots
#pragma unroll
      for (int it = 0; it < 6; ++it) {
        int s = it * 256 + tid;
        int t3 = s >> 9, rem = s & 511;
        int co = rem >> 2, q = rem & 3;
        int qg = q ^ ((co >> 1) & 3);
        gll16(wtu + ((size_t)((ky * 3 + t3) * 128 + co)) * 128 + cc * 32 + qg * 8,
              Bl + s * 16);
      }
      __syncthreads();
#pragma unroll
      for (int kx = 0; kx < 3; ++kx) {
        bf16x8 aF[4], bF[4];
#pragma unroll
        for (int mb = 0; mb < 4; ++mb) aF[mb] = *(const bf16x8*)(Al + aoff[kx][mb]);
#pragma unroll
        for (int nb = 0; nb < 4; ++nb) bF[nb] = *(const bf16x8*)(Bl + boff[kx][nb]);
#pragma unroll
        for (int mb = 0; mb < 4; ++mb)
#pragma unroll
          for (int nb = 0; nb < 4; ++nb)
            acc[mb][nb] = __builtin_amdgcn_mfma_f32_16x16x32_bf16(
                bF[nb], aF[mb], acc[mb][nb], 0, 0, 0);
      }
    }
  }

  // ---- epilogue: acc -> LDS bf16 tile [128 px][130] -> coalesced stores ----
  __syncthreads();  // all MFMA LDS reads done; reuse smem
  unsigned short* tb = (unsigned short*)smem;     // 33280 B
  float* sg = (float*)(smem + 33280);             // 64 B
  if (tid < 16) sg[tid] = 0.f;
  float sv[4] = {0, 0, 0, 0}, qv[4] = {0, 0, 0, 0};
#pragma unroll
  for (int mb = 0; mb < 4; ++mb) {
    int px = wm * 64 + mb * 16 + rl;
#pragma unroll
    for (int nb = 0; nb < 4; ++nb) {
      int co0 = wn * 64 + nb * 16 + kg * 4;
      u16x4 pk;
#pragma unroll
      for (int j = 0; j < 4; ++j) {
        float v = acc[mb][nb][j];
        pk[j] = f2b(v);
        sv[nb] += v; qv[nb] += v * v;
      }
      *(u16x4*)&tb[px * 130 + co0] = pk;
    }
  }
  __syncthreads();
  {
    size_t gbase = ((size_t)b * 128 + h0) * 128 * 128;  // u16 elems
#pragma unroll
    for (int k = 0; k < 8; ++k) {
      int go = wid * 4096 + k * 512 + lane * 8;  // u16 units; 1KB/wave-instr
      int px = go >> 7, cu = go & 127;
      u16x8 vv = *(const u16x8*)&tb[px * 130 + cu];
      *(u16x8*)(outu + gbase + go) = vv;
    }
  }
#pragma unroll
  for (int nb = 0; nb < 4; ++nb) {
    float a = sv[nb], q = qv[nb];
#pragma unroll
    for (int o = 32; o > 0; o >>= 1) { a += __shfl_down(a, o); q += __shfl_down(q, o); }
    if (lane == 0) {
      int g = wn * 4 + nb;
      atomicAdd(&sg[g * 2 + 0], a);
      atomicAdd(&sg[g * 2 + 1], q);
    }
  }
  __syncthreads();
  if (tid < 16) partials[(size_t)nid * 16 + tid] = sg[tid];
}

// ---- reduce per-block partials -> stats; blockIdx = set ------------------
__global__ void k_redstats(const float* __restrict__ partials, float* __restrict__ stats,
                           int nper) {
  int set = blockIdx.x;
  const float* p = partials + (size_t)set * 8 * nper * 16;
  float* st = stats + set * 128;
  int t = threadIdx.x;
  int o = t >> 2, j = t & 3;  // o: 0..127 = b*16+slot
  int b = o >> 4, slot = o & 15;
  int chunk = nper >> 2;
  float s = 0.f;
  for (int i = j * chunk; i < (j + 1) * chunk; ++i)
    s += p[((size_t)b * nper + i) * 16 + slot];
  s += __shfl_xor(s, 1);
  s += __shfl_xor(s, 2);
  if (j == 0) st[o] = s;
}

// ---- reduce merge partials (8192 blocks x 16) -> stats2[b*16+slot] --------
__global__ void k_redstats2(const float* __restrict__ p2, float* __restrict__ st) {
  int o = blockIdx.x;  // 0..127
  int b = o >> 4, slot = o & 15;
  float s = 0.f;
  for (int i = threadIdx.x; i < 1024; i += 256)
    s += p2[((size_t)b * 1024 + i) * 16 + slot];
#pragma unroll
  for (int off = 32; off > 0; off >>= 1) s += __shfl_down(s, off);
  __shared__ float wsm[4];
  int lane = threadIdx.x & 63, wv = threadIdx.x >> 6;
  if (lane == 0) wsm[wv] = s;
  __syncthreads();
  if (threadIdx.x == 0) st[o] = wsm[0] + wsm[1] + wsm[2] + wsm[3];
}

// ---- merge NEXP experts: merged (+)= sum_e w_e*silu(gn_e(conv_e)) ---------
// flags: bit0 = accumulate; bit1 = last pass (add x, write merge-GN partials)
template <int NEXP>
__global__ void k_merge(const unsigned short* __restrict__ c0,
                        const unsigned short* __restrict__ c1,
                        const unsigned short* __restrict__ c2,
                        const unsigned short* __restrict__ c3,
                        const float* __restrict__ st, const float* __restrict__ eg,
                        const float* __restrict__ eb, const float* __restrict__ wts,
                        unsigned short* __restrict__ merged,
                        const unsigned short* __restrict__ xp,
                        float* __restrict__ partials2, int e0, int flags) {
  __shared__ float sg[16];
  int tid = threadIdx.x;
  if (tid < 16) sg[tid] = 0.f;
  __syncthreads();
  size_t idx = ((size_t)blockIdx.x * 256 + tid) * 8;
  int co0 = (int)(idx & 127);
  size_t pix = idx >> 7;
  int w = (int)(pix & 127), h = (int)((pix >> 7) & 127), b = (int)(pix >> 14);
  int g = co0 >> 4;
  const float cnt = 16.f * 128.f * 128.f;
  int patch = (h >> 4) * 8 + (w >> 4);
  const unsigned short* cs[4] = {c0, c1, c2, c3};
  float a[8] = {0, 0, 0, 0, 0, 0, 0, 0};
#pragma unroll
  for (int k = 0; k < NEXP; ++k) {
    int e = e0 + k;
    float mean = st[e * 128 + (b * 8 + g) * 2] / cnt;
    float var = st[e * 128 + (b * 8 + g) * 2 + 1] / cnt - mean * mean;
    float rstd = rsqrtf(var + 1e-5f);
    float we = wts[patch * 8 + e];
    u16x8 cv = *(const u16x8*)(cs[k] + idx);
#pragma unroll
    for (int i = 0; i < 8; ++i) {
      float xn = (b2f(cv[i]) - mean) * rstd * eg[e * 128 + co0 + i] + eb[e * 128 + co0 + i];
      a[i] += we * silu_f(xn);
    }
  }
  if (flags & 1) {
    u16x8 mv = *(const u16x8*)(merged + idx);
#pragma unroll
    for (int i = 0; i < 8; ++i) a[i] += b2f(mv[i]);
  }
  u16x8 out;
  float s = 0.f, q = 0.f;
  if (flags & 2) {
    const unsigned short* xr =
        xp + (((size_t)b * 130 + h + 1) * 130 + (w + 1)) * 128 + co0;
    u16x8 xv = *(const u16x8*)xr;
#pragma unroll
    for (int i = 0; i < 8; ++i) {
      a[i] += b2f(xv[i]);
      out[i] = f2b(a[i]);
      float rv = b2f(out[i]);
      s += rv; q += rv * rv;
    }
  } else {
#pragma unroll
    for (int i = 0; i < 8; ++i) out[i] = f2b(a[i]);
  }
  *(u16x8*)(merged + idx) = out;
  if (flags & 2) {
    atomicAdd(&sg[g * 2 + 0], s);
    atomicAdd(&sg[g * 2 + 1], q);
    __syncthreads();
    if (tid < 16) partials2[(size_t)blockIdx.x * 16 + tid] = sg[tid];
  }
}

// ---- y = x + gamma*silu(gn(M)); write bf16 y into padded buffer (in place) -
__global__ void k_ypass(const unsigned short* __restrict__ merged,
                        unsigned short* __restrict__ xp,
                        const float* __restrict__ st, const float* __restrict__ mg,
                        const float* __restrict__ mbv, const float* __restrict__ gptr) {
  size_t idx = ((size_t)blockIdx.x * 256 + threadIdx.x) * 8;
  int co0 = (int)(idx & 127);
  size_t pix = idx >> 7;
  int w = (int)(pix & 127), h = (int)((pix >> 7) & 127), b = (int)(pix >> 14);
  int g = co0 >> 4;
  const float cnt = 16.f * 128.f * 128.f;
  float mean = st[(b * 8 + g) * 2] / cnt;
  float var = st[(b * 8 + g) * 2 + 1] / cnt - mean * mean;
  float rstd = rsqrtf(var + 1e-5f);
  float gm = gptr[0];
  unsigned short* xr = xp + (((size_t)b * 130 + h + 1) * 130 + (w + 1)) * 128 + co0;
  u16x8 xv = *(const u16x8*)xr;
  u16x8 mv = *(const u16x8*)(merged + idx);
  u16x8 yv;
#pragma unroll
  for (int i = 0; i < 8; ++i) {
    float xf = b2f(xv[i]);
    float M = b2f(mv[i]);
    float xn = (M - mean) * rstd * mg[co0 + i] + mbv[co0 + i];
    yv[i] = f2b(xf + gm * silu_f(xn));
  }
  *(u16x8*)xr = yv;
}

// ---- final: out = silu(gn3(conv3)), NHWC bf16 -> NCHW f32 via LDS transpose
__global__ void k_final(const __hip_bfloat16* __restrict__ conv, const float* __restrict__ st,
                        const float* __restrict__ pg, const float* __restrict__ pb,
                        float* __restrict__ out) {
  int bx = blockIdx.x;
  int wb = bx & 1, h = (bx >> 1) & 127, b = bx >> 8;
  int w0 = wb * 64;
  __shared__ float t[64][129];
  int tid = threadIdx.x;
  const float cnt = 16.f * 128.f * 128.f;
  const unsigned short* cu = (const unsigned short*)conv;
#pragma unroll
  for (int r = 0; r < 32; ++r) {
    int e2 = r * 256 + tid;
    int co = e2 & 127, wl = e2 >> 7;
    int g = co >> 4;
    float mean = st[(b * 8 + g) * 2] / cnt;
    float var = st[(b * 8 + g) * 2 + 1] / cnt - mean * mean;
    float rstd = rsqrtf(var + 1e-5f);
    float v = b2f(cu[(((size_t)b * 128 + h) * 128 + w0 + wl) * 128 + co]);
    float xn = (v - mean) * rstd * pg[co] + pb[co];
    t[wl][co] = silu_f(xn);
  }
  __syncthreads();
#pragma unroll
  for (int r = 0; r < 8; ++r) {
    int f = r * 256 + tid;
    int jb = f & 15, co = f >> 4;
    f32x4 o;
#pragma unroll
    for (int j = 0; j < 4; ++j) o[j] = t[jb * 4 + j][co];
    *(f32x4*)&out[(((size_t)b * 128 + co) * 128 + h) * 128 + w0 + jb * 4] = o;
  }
}

// ---------------------------------------------------------------------------
extern "C" void kernel_launch(void* const* d_in, const int* in_sizes, int n_in,
                              void* d_out, int out_size, void* d_ws, size_t ws_size,
                              hipStream_t stream) {
  const float* x        = (const float*)d_in[0];
  const float* expert_w = (const float*)d_in[1];
  const float* expert_g = (const float*)d_in[2];
  const float* expert_b = (const float*)d_in[3];
  const float* router_w = (const float*)d_in[4];
  const float* router_b = (const float*)d_in[5];
  const float* merge_g  = (const float*)d_in[6];
  const float* merge_b  = (const float*)d_in[7];
  const float* gamma    = (const float*)d_in[8];
  const float* post_w   = (const float*)d_in[9];
  const float* post_g   = (const float*)d_in[10];
  const float* post_b   = (const float*)d_in[11];

  char* ws = (char*)d_ws;
  float* wts            = (float*)(ws + 0);          // 2048
  float* stats          = (float*)(ws + 2048);       // 5120 (10 x 128 f32)
  float* partials       = (float*)(ws + 8192);       // 655,360 (10 regions x 1024 x 16)
  float* partials2      = (float*)(ws + 663552);     // 524,288 (8192 x 16)
  unsigned short* wtb   = (unsigned short*)(ws + 1187840);   // 2,654,208
  unsigned short* xpad  = (unsigned short*)(ws + 3842048);   // 34,611,200 + 8,192 pad
  unsigned short* bufs[4];
  unsigned short* merged;
  const size_t BUF0 = 38461440ull;
  const size_t NEED2 = BUF0 + 3ull * 33554432ull;
  const size_t NEED4 = BUF0 + 5ull * 33554432ull;
  int nbuf = (ws_size >= NEED4) ? 4 : 2;
  bufs[0] = (unsigned short*)(ws + BUF0);
  bufs[1] = (unsigned short*)(ws + BUF0 + 33554432ull);
  if (nbuf == 4) {
    bufs[2] = (unsigned short*)(ws + BUF0 + 2ull * 33554432ull);
    bufs[3] = (unsigned short*)(ws + BUF0 + 3ull * 33554432ull);
    merged  = (unsigned short*)(ws + BUF0 + 4ull * 33554432ull);
  } else {
    bufs[2] = bufs[0]; bufs[3] = bufs[1];
    merged  = (unsigned short*)(ws + BUF0 + 2ull * 33554432ull);
  }
  if (ws_size < NEED2) {  // graceful fallback, no corruption
    hipMemsetAsync(d_out, 0, (size_t)out_size * 4, stream);
    return;
  }

  hipMemsetAsync(xpad, 0, 34619392ull, stream);
  k_router<<<1, 64, 0, stream>>>(router_w, router_b, wts);
  k_build_xpad<<<4096, 256, 0, stream>>>(x, (__hip_bfloat16*)xpad);
  k_build_w<<<4608, 256, 0, stream>>>(expert_w, (__hip_bfloat16*)wtb, 1179648);
  k_build_w<<<576, 256, 0, stream>>>(post_w, (__hip_bfloat16*)(wtb + 1179648), 147456);

  if (nbuf == 4) {
    for (int p = 0; p < 2; ++p) {
      for (int k = 0; k < 4; ++k) {
        int e = p * 4 + k;
        k_conv<<<1024, 256, 0, stream>>>(xpad, wtb + (size_t)e * 147456, bufs[k],
                                         partials + (size_t)e * 16384);
      }
      k_redstats<<<4, 512, 0, stream>>>(partials + (size_t)p * 4 * 16384,
                                        stats + p * 4 * 128, 128);
      int flags = (p > 0 ? 1 : 0) | (p == 1 ? 2 : 0);
      k_merge<4><<<8192, 256, 0, stream>>>(bufs[0], bufs[1], bufs[2], bufs[3], stats,
                                           expert_g, expert_b, wts, merged, xpad,
                                           partials2, p * 4, flags);
    }
  } else {
    for (int p = 0; p < 4; ++p) {
      for (int k = 0; k < 2; ++k) {
        int e = p * 2 + k;
        k_conv<<<1024, 256, 0, stream>>>(xpad, wtb + (size_t)e * 147456, bufs[k],
                                         partials + (size_t)e * 16384);
      }
      k_redstats<<<2, 512, 0, stream>>>(partials + (size_t)p * 2 * 16384,
                                        stats + p * 2 * 128, 128);
      int flags = (p > 0 ? 1 : 0) | (p == 3 ? 2 : 0);
      k_merge<2><<<8192, 256, 0, stream>>>(bufs[0], bufs[1], bufs[0], bufs[1], stats,
                                           expert_g, expert_b, wts, merged, xpad,
                                           partials2, p * 2, flags);
    }
  }
  k_redstats2<<<128, 256, 0, stream>>>(partials2, stats + 8 * 128);
  k_ypass<<<8192, 256, 0, stream>>>(merged, xpad, stats + 8 * 128, merge_g, merge_b, gamma);
  k_conv<<<1024, 256, 0, stream>>>(xpad, wtb + 1179648ull, bufs[0],
                                   partials + (size_t)8 * 16384);
  k_redstats<<<1, 512, 0, stream>>>(partials + (size_t)8 * 16384, stats + 9 * 128, 128);
  k_final<<<2048, 256, 0, stream>>>((const __hip_bfloat16*)bufs[0], stats + 9 * 128,
                                    post_g, post_b, (float*)d_out);
}

// Round 5
// 648.194 us; speedup vs baseline: 3.2221x; 2.0400x over previous
//
#include <hip/hip_runtime.h>
#include <hip/hip_bf16.h>

// ---------------------------------------------------------------------------
// PCELayer. Convs as implicit GEMM on bf16 MFMA.
// R5: k_conv rebuilt on the m97 double-buffered schedule:
//   stage(u+1) || compute(u), ONE barrier per stage-unit.
//   stage-unit (cc,ky): A = 1 row x 160px x 32ci (10.25KB) + B = 3 taps x
//   128co x 32ci (24.6KB) = 35KB; dbuf 70KB -> 2 blocks/CU; 48 MFMA/wave/unit.
// Fast stages keep the shared B slice alive in per-XCD L2 (breaks the R3/R4
// L2 death spiral that inflated FETCH to 283MB).
// ---------------------------------------------------------------------------

typedef __attribute__((ext_vector_type(8))) short bf16x8;
typedef __attribute__((ext_vector_type(4))) float f32x4;
typedef __attribute__((ext_vector_type(8))) unsigned short u16x8;
typedef __attribute__((ext_vector_type(4))) unsigned short u16x4;

__device__ __forceinline__ float b2f(unsigned short u) {
  unsigned int v = ((unsigned int)u) << 16;
  return __builtin_bit_cast(float, v);
}
__device__ __forceinline__ unsigned short f2b(float f) {
  __hip_bfloat16 h = __float2bfloat16(f);
  return __builtin_bit_cast(unsigned short, h);
}
__device__ __forceinline__ float silu_f(float x) {
  return x / (1.f + __expf(-x));
}
__device__ __forceinline__ void gll16(const void* g, void* l) {
  __builtin_amdgcn_global_load_lds(
      (const __attribute__((address_space(1))) unsigned int*)g,
      (__attribute__((address_space(3))) unsigned int*)l, 16, 0, 0);
}

// ---- router: 64 patches x 8 experts -------------------------------------
__global__ void k_router(const float* __restrict__ rw, const float* __restrict__ rb,
                         float* __restrict__ wts) {
  int t = threadIdx.x;
  if (t >= 64) return;
  int py = t >> 3, px = t & 7;
  float cy = (py + 0.5f) / 8.f, cx = (px + 0.5f) / 8.f;
  const float PI = 3.14159265358979323846f;
  float f[16];
#pragma unroll
  for (int k = 0; k < 4; ++k) {
    float fr = (float)(1 << k) * PI;
    f[k]      = sinf(cy * fr);
    f[4 + k]  = cosf(cy * fr);
    f[8 + k]  = sinf(cx * fr);
    f[12 + k] = cosf(cx * fr);
  }
  float lg[8], mx = -1e30f;
#pragma unroll
  for (int e = 0; e < 8; ++e) {
    float a = rb[e];
#pragma unroll
    for (int k = 0; k < 16; ++k) a += f[k] * rw[k * 8 + e];
    lg[e] = a; mx = fmaxf(mx, a);
  }
  float s = 0.f;
#pragma unroll
  for (int e = 0; e < 8; ++e) { lg[e] = __expf(lg[e] - mx); s += lg[e]; }
  float inv = 1.f / s;
#pragma unroll
  for (int e = 0; e < 8; ++e) wts[t * 8 + e] = lg[e] * inv;
}

// ---- x (NCHW f32) -> padded NHWC bf16 [8][130][130][128] ------------------
__global__ void k_build_xpad(const float* __restrict__ x, __hip_bfloat16* __restrict__ xp) {
  int bx = blockIdx.x;
  int wb = bx & 1, cib = (bx >> 1) & 1;
  int h = (bx >> 2) & 127, b = bx >> 9;
  int w0 = wb * 64, ci0 = cib * 64;
  __shared__ float t[64][65];
  int tid = threadIdx.x;
#pragma unroll
  for (int r = 0; r < 16; ++r) {
    int idx = r * 256 + tid;
    int i = idx >> 6, j = idx & 63;  // i: ci, j: w
    t[i][j] = x[(((size_t)b * 128 + ci0 + i) * 128 + h) * 128 + w0 + j];
  }
  __syncthreads();
  unsigned short* xpu = (unsigned short*)xp;
#pragma unroll
  for (int r = 0; r < 16; ++r) {
    int idx = r * 256 + tid;
    int j = idx >> 6, i = idx & 63;  // j: w, i: ci
    xpu[(((size_t)b * 130 + h + 1) * 130 + (w0 + j + 1)) * 128 + ci0 + i] = f2b(t[i][j]);
  }
}

// ---- weights [e][co][ci][3][3] f32 -> [e][tap][co][ci] bf16 ---------------
__global__ void k_build_w(const float* __restrict__ src, __hip_bfloat16* __restrict__ dst,
                          int total) {
  int o = blockIdx.x * 256 + threadIdx.x;
  if (o >= total) return;
  int ci = o & 127, co = (o >> 7) & 127;
  int r = o >> 14; int tp = r % 9, e = r / 9;
  ((unsigned short*)dst)[o] =
      f2b(src[(((size_t)e * 128 + co) * 128 + ci) * 9 + tp]);
}

// ---- conv3x3 implicit GEMM: 128 px (1 row) x 128 cout, m97 dbuf schedule --
__global__ __launch_bounds__(256, 2) void k_conv(
    const unsigned short* __restrict__ xpu, const unsigned short* __restrict__ wtu,
    unsigned short* __restrict__ outu, float* __restrict__ partials) {
  __shared__ __align__(16) char smem[69632];  // 2 x (A 10240 + B 24576)
  const int bx0 = blockIdx.x;
  const int nid = (bx0 & 7) * 128 + (bx0 >> 3);  // XCD-chunk remap
  const int b = nid >> 7, h0 = nid & 127;
  const int tid = threadIdx.x;
  const int lane = tid & 63, wid = tid >> 6;
  const int wm = wid >> 1, wn = wid & 1;
  const int rl = lane & 15, kg = lane >> 4;

  // LDS read byte-offsets within a buffer (unit-invariant)
  int aoff[3][4];  // [kx][mb]
  int boff[3][4];  // [kx][nb]
#pragma unroll
  for (int mb = 0; mb < 4; ++mb) {
    int w = wm * 64 + mb * 16 + rl;
#pragma unroll
    for (int kx = 0; kx < 3; ++kx) {
      int px = w + kx;
      aoff[kx][mb] = (px * 4 + (kg ^ ((px >> 1) & 3))) * 16;
    }
  }
#pragma unroll
  for (int kx = 0; kx < 3; ++kx)
#pragma unroll
    for (int nb = 0; nb < 4; ++nb) {
      int co = wn * 64 + nb * 16 + rl;
      boff[kx][nb] = (10240 + ((kx * 128 + co) * 4 + (kg ^ ((co >> 1) & 3))) * 16);
    }

  f32x4 acc[4][4] = {};  // [mb][nb]; operands swapped: lane holds 4 cout

  // stage unit u = cc*3 + ky into buffer bi
  auto stage = [&](int bi, int u) {
    const int cc = u >> 2 ? (u / 3) : 0;  // placeholder (recomputed below)
    (void)cc;
  };
  (void)stage;

#define STAGE(bi, u)                                                          \
  {                                                                           \
    const int cc_ = (u) / 3, ky_ = (u) - cc_ * 3;                             \
    char* Al_ = smem + (bi) * 34816;                                          \
    char* Bl_ = Al_ + 10240;                                                  \
    const size_t arow_ = (size_t)(b * 130 + h0 + ky_) * 130;                  \
    _Pragma("unroll")                                                         \
    for (int it = 0; it < 3; ++it) {                                          \
      int s = it * 256 + tid;                                                 \
      if (it < 2 || tid < 128) {                                              \
        int px = s >> 2, q = s & 3;                                           \
        int qg = q ^ ((px >> 1) & 3);                                         \
        gll16(xpu + (arow_ + px) * 128 + cc_ * 32 + qg * 8, Al_ + s * 16);    \
      }                                                                       \
    }                                                                         \
    _Pragma("unroll")                                                         \
    for (int it = 0; it < 6; ++it) {                                          \
      int s = it * 256 + tid;                                                 \
      int t3 = s >> 9, rem = s & 511;                                         \
      int co = rem >> 2, q = rem & 3;                                         \
      int qg = q ^ ((co >> 1) & 3);                                           \
      gll16(wtu + ((size_t)((ky_ * 3 + t3) * 128 + co)) * 128 + cc_ * 32 +    \
                qg * 8,                                                       \
            Bl_ + s * 16);                                                    \
    }                                                                         \
  }

  STAGE(0, 0);
  for (int u = 0; u < 12; ++u) {
    const int cur = u & 1;
    __syncthreads();                 // stage(u) complete; buf[cur^1] free
    if (u + 1 < 12) STAGE(cur ^ 1, u + 1);  // prefetch flies under compute
    char* Al = smem + cur * 34816;
#pragma unroll
    for (int kx = 0; kx < 3; ++kx) {
      bf16x8 aF[4], bF[4];
#pragma unroll
      for (int mb = 0; mb < 4; ++mb) aF[mb] = *(const bf16x8*)(Al + aoff[kx][mb]);
#pragma unroll
      for (int nb = 0; nb < 4; ++nb) bF[nb] = *(const bf16x8*)(Al + boff[kx][nb]);
#pragma unroll
      for (int mb = 0; mb < 4; ++mb)
#pragma unroll
        for (int nb = 0; nb < 4; ++nb)
          acc[mb][nb] = __builtin_amdgcn_mfma_f32_16x16x32_bf16(
              bF[nb], aF[mb], acc[mb][nb], 0, 0, 0);
    }
  }
#undef STAGE

  // ---- epilogue: acc -> LDS bf16 tile [128 px][130] -> coalesced stores ----
  __syncthreads();  // all LDS reads done; reuse smem
  unsigned short* tb = (unsigned short*)smem;     // 33280 B
  float* sg = (float*)(smem + 33280);             // 64 B
  if (tid < 16) sg[tid] = 0.f;
  float sv[4] = {0, 0, 0, 0}, qv[4] = {0, 0, 0, 0};
#pragma unroll
  for (int mb = 0; mb < 4; ++mb) {
    int px = wm * 64 + mb * 16 + rl;
#pragma unroll
    for (int nb = 0; nb < 4; ++nb) {
      int co0 = wn * 64 + nb * 16 + kg * 4;
      u16x4 pk;
#pragma unroll
      for (int j = 0; j < 4; ++j) {
        float v = acc[mb][nb][j];
        pk[j] = f2b(v);
        sv[nb] += v; qv[nb] += v * v;
      }
      *(u16x4*)&tb[px * 130 + co0] = pk;
    }
  }
  __syncthreads();
  {
    size_t gbase = ((size_t)b * 128 + h0) * 128 * 128;  // u16 elems
#pragma unroll
    for (int k = 0; k < 16; ++k) {
      int go = wid * 4096 + (k >> 1) * 512 + lane * 8;  // two half-waves/k? no:
      // simple: 16384 u16 / (256 thr * 8) = 8 iters; keep 8.
      if (k >= 8) break;
      go = wid * 4096 + k * 512 + lane * 8;
      int px = go >> 7, cu = go & 127;
      u16x8 vv = *(const u16x8*)&tb[px * 130 + cu];
      *(u16x8*)(outu + gbase + go) = vv;
    }
  }
#pragma unroll
  for (int nb = 0; nb < 4; ++nb) {
    float a = sv[nb], q = qv[nb];
#pragma unroll
    for (int o = 32; o > 0; o >>= 1) { a += __shfl_down(a, o); q += __shfl_down(q, o); }
    if (lane == 0) {
      int g = wn * 4 + nb;
      atomicAdd(&sg[g * 2 + 0], a);
      atomicAdd(&sg[g * 2 + 1], q);
    }
  }
  __syncthreads();
  if (tid < 16) partials[(size_t)nid * 16 + tid] = sg[tid];
}

// ---- reduce per-block partials -> stats; blockIdx = set ------------------
__global__ void k_redstats(const float* __restrict__ partials, float* __restrict__ stats,
                           int nper) {
  int set = blockIdx.x;
  const float* p = partials + (size_t)set * 8 * nper * 16;
  float* st = stats + set * 128;
  int t = threadIdx.x;
  int o = t >> 2, j = t & 3;  // o: 0..127 = b*16+slot
  int b = o >> 4, slot = o & 15;
  int chunk = nper >> 2;
  float s = 0.f;
  for (int i = j * chunk; i < (j + 1) * chunk; ++i)
    s += p[((size_t)b * nper + i) * 16 + slot];
  s += __shfl_xor(s, 1);
  s += __shfl_xor(s, 2);
  if (j == 0) st[o] = s;
}

// ---- reduce merge partials (8192 blocks x 16) -> stats2[b*16+slot] --------
__global__ void k_redstats2(const float* __restrict__ p2, float* __restrict__ st) {
  int o = blockIdx.x;  // 0..127
  int b = o >> 4, slot = o & 15;
  float s = 0.f;
  for (int i = threadIdx.x; i < 1024; i += 256)
    s += p2[((size_t)b * 1024 + i) * 16 + slot];
#pragma unroll
  for (int off = 32; off > 0; off >>= 1) s += __shfl_down(s, off);
  __shared__ float wsm[4];
  int lane = threadIdx.x & 63, wv = threadIdx.x >> 6;
  if (lane == 0) wsm[wv] = s;
  __syncthreads();
  if (threadIdx.x == 0) st[o] = wsm[0] + wsm[1] + wsm[2] + wsm[3];
}

// ---- merge NEXP experts: merged (+)= sum_e w_e*silu(gn_e(conv_e)) ---------
// flags: bit0 = accumulate; bit1 = last pass (add x, write merge-GN partials)
template <int NEXP>
__global__ void k_merge(const unsigned short* __restrict__ c0,
                        const unsigned short* __restrict__ c1,
                        const unsigned short* __restrict__ c2,
                        const unsigned short* __restrict__ c3,
                        const float* __restrict__ st, const float* __restrict__ eg,
                        const float* __restrict__ eb, const float* __restrict__ wts,
                        unsigned short* __restrict__ merged,
                        const unsigned short* __restrict__ xp,
                        float* __restrict__ partials2, int e0, int flags) {
  __shared__ float sg[16];
  int tid = threadIdx.x;
  if (tid < 16) sg[tid] = 0.f;
  __syncthreads();
  size_t idx = ((size_t)blockIdx.x * 256 + tid) * 8;
  int co0 = (int)(idx & 127);
  size_t pix = idx >> 7;
  int w = (int)(pix & 127), h = (int)((pix >> 7) & 127), b = (int)(pix >> 14);
  int g = co0 >> 4;
  const float cnt = 16.f * 128.f * 128.f;
  int patch = (h >> 4) * 8 + (w >> 4);
  const unsigned short* cs[4] = {c0, c1, c2, c3};
  float a[8] = {0, 0, 0, 0, 0, 0, 0, 0};
#pragma unroll
  for (int k = 0; k < NEXP; ++k) {
    int e = e0 + k;
    float mean = st[e * 128 + (b * 8 + g) * 2] / cnt;
    float var = st[e * 128 + (b * 8 + g) * 2 + 1] / cnt - mean * mean;
    float rstd = rsqrtf(var + 1e-5f);
    float we = wts[patch * 8 + e];
    u16x8 cv = *(const u16x8*)(cs[k] + idx);
#pragma unroll
    for (int i = 0; i < 8; ++i) {
      float xn = (b2f(cv[i]) - mean) * rstd * eg[e * 128 + co0 + i] + eb[e * 128 + co0 + i];
      a[i] += we * silu_f(xn);
    }
  }
  if (flags & 1) {
    u16x8 mv = *(const u16x8*)(merged + idx);
#pragma unroll
    for (int i = 0; i < 8; ++i) a[i] += b2f(mv[i]);
  }
  u16x8 out;
  float s = 0.f, q = 0.f;
  if (flags & 2) {
    const unsigned short* xr =
        xp + (((size_t)b * 130 + h + 1) * 130 + (w + 1)) * 128 + co0;
    u16x8 xv = *(const u16x8*)xr;
#pragma unroll
    for (int i = 0; i < 8; ++i) {
      a[i] += b2f(xv[i]);
      out[i] = f2b(a[i]);
      float rv = b2f(out[i]);
      s += rv; q += rv * rv;
    }
  } else {
#pragma unroll
    for (int i = 0; i < 8; ++i) out[i] = f2b(a[i]);
  }
  *(u16x8*)(merged + idx) = out;
  if (flags & 2) {
    atomicAdd(&sg[g * 2 + 0], s);
    atomicAdd(&sg[g * 2 + 1], q);
    __syncthreads();
    if (tid < 16) partials2[(size_t)blockIdx.x * 16 + tid] = sg[tid];
  }
}

// ---- y = x + gamma*silu(gn(M)); write bf16 y into padded buffer (in place) -
__global__ void k_ypass(const unsigned short* __restrict__ merged,
                        unsigned short* __restrict__ xp,
                        const float* __restrict__ st, const float* __restrict__ mg,
                        const float* __restrict__ mbv, const float* __restrict__ gptr) {
  size_t idx = ((size_t)blockIdx.x * 256 + threadIdx.x) * 8;
  int co0 = (int)(idx & 127);
  size_t pix = idx >> 7;
  int w = (int)(pix & 127), h = (int)((pix >> 7) & 127), b = (int)(pix >> 14);
  int g = co0 >> 4;
  const float cnt = 16.f * 128.f * 128.f;
  float mean = st[(b * 8 + g) * 2] / cnt;
  float var = st[(b * 8 + g) * 2 + 1] / cnt - mean * mean;
  float rstd = rsqrtf(var + 1e-5f);
  float gm = gptr[0];
  unsigned short* xr = xp + (((size_t)b * 130 + h + 1) * 130 + (w + 1)) * 128 + co0;
  u16x8 xv = *(const u16x8*)xr;
  u16x8 mv = *(const u16x8*)(merged + idx);
  u16x8 yv;
#pragma unroll
  for (int i = 0; i < 8; ++i) {
    float xf = b2f(xv[i]);
    float M = b2f(mv[i]);
    float xn = (M - mean) * rstd * mg[co0 + i] + mbv[co0 + i];
    yv[i] = f2b(xf + gm * silu_f(xn));
  }
  *(u16x8*)xr = yv;
}

// ---- final: out = silu(gn3(conv3)), NHWC bf16 -> NCHW f32 via LDS transpose
__global__ void k_final(const __hip_bfloat16* __restrict__ conv, const float* __restrict__ st,
                        const float* __restrict__ pg, const float* __restrict__ pb,
                        float* __restrict__ out) {
  int bx = blockIdx.x;
  int wb = bx & 1, h = (bx >> 1) & 127, b = bx >> 8;
  int w0 = wb * 64;
  __shared__ float t[64][129];
  int tid = threadIdx.x;
  const float cnt = 16.f * 128.f * 128.f;
  const unsigned short* cu = (const unsigned short*)conv;
#pragma unroll
  for (int r = 0; r < 32; ++r) {
    int e2 = r * 256 + tid;
    int co = e2 & 127, wl = e2 >> 7;
    int g = co >> 4;
    float mean = st[(b * 8 + g) * 2] / cnt;
    float var = st[(b * 8 + g) * 2 + 1] / cnt - mean * mean;
    float rstd = rsqrtf(var + 1e-5f);
    float v = b2f(cu[(((size_t)b * 128 + h) * 128 + w0 + wl) * 128 + co]);
    float xn = (v - mean) * rstd * pg[co] + pb[co];
    t[wl][co] = silu_f(xn);
  }
  __syncthreads();
#pragma unroll
  for (int r = 0; r < 8; ++r) {
    int f = r * 256 + tid;
    int jb = f & 15, co = f >> 4;
    f32x4 o;
#pragma unroll
    for (int j = 0; j < 4; ++j) o[j] = t[jb * 4 + j][co];
    *(f32x4*)&out[(((size_t)b * 128 + co) * 128 + h) * 128 + w0 + jb * 4] = o;
  }
}

// ---------------------------------------------------------------------------
extern "C" void kernel_launch(void* const* d_in, const int* in_sizes, int n_in,
                              void* d_out, int out_size, void* d_ws, size_t ws_size,
                              hipStream_t stream) {
  const float* x        = (const float*)d_in[0];
  const float* expert_w = (const float*)d_in[1];
  const float* expert_g = (const float*)d_in[2];
  const float* expert_b = (const float*)d_in[3];
  const float* router_w = (const float*)d_in[4];
  const float* router_b = (const float*)d_in[5];
  const float* merge_g  = (const float*)d_in[6];
  const float* merge_b  = (const float*)d_in[7];
  const float* gamma    = (const float*)d_in[8];
  const float* post_w   = (const float*)d_in[9];
  const float* post_g   = (const float*)d_in[10];
  const float* post_b   = (const float*)d_in[11];

  char* ws = (char*)d_ws;
  float* wts            = (float*)(ws + 0);          // 2048
  float* stats          = (float*)(ws + 2048);       // 5120 (10 x 128 f32)
  float* partials       = (float*)(ws + 8192);       // 655,360 (10 regions x 1024 x 16)
  float* partials2      = (float*)(ws + 663552);     // 524,288 (8192 x 16)
  unsigned short* wtb   = (unsigned short*)(ws + 1187840);   // 2,654,208
  unsigned short* xpad  = (unsigned short*)(ws + 3842048);   // 34,611,200 + 8,192 pad
  unsigned short* bufs[4];
  unsigned short* merged;
  const size_t BUF0 = 38461440ull;
  const size_t NEED2 = BUF0 + 3ull * 33554432ull;
  const size_t NEED4 = BUF0 + 5ull * 33554432ull;
  int nbuf = (ws_size >= NEED4) ? 4 : 2;
  bufs[0] = (unsigned short*)(ws + BUF0);
  bufs[1] = (unsigned short*)(ws + BUF0 + 33554432ull);
  if (nbuf == 4) {
    bufs[2] = (unsigned short*)(ws + BUF0 + 2ull * 33554432ull);
    bufs[3] = (unsigned short*)(ws + BUF0 + 3ull * 33554432ull);
    merged  = (unsigned short*)(ws + BUF0 + 4ull * 33554432ull);
  } else {
    bufs[2] = bufs[0]; bufs[3] = bufs[1];
    merged  = (unsigned short*)(ws + BUF0 + 2ull * 33554432ull);
  }
  if (ws_size < NEED2) {  // graceful fallback, no corruption
    hipMemsetAsync(d_out, 0, (size_t)out_size * 4, stream);
    return;
  }

  hipMemsetAsync(xpad, 0, 34619392ull, stream);
  k_router<<<1, 64, 0, stream>>>(router_w, router_b, wts);
  k_build_xpad<<<4096, 256, 0, stream>>>(x, (__hip_bfloat16*)xpad);
  k_build_w<<<4608, 256, 0, stream>>>(expert_w, (__hip_bfloat16*)wtb, 1179648);
  k_build_w<<<576, 256, 0, stream>>>(post_w, (__hip_bfloat16*)(wtb + 1179648), 147456);

  if (nbuf == 4) {
    for (int p = 0; p < 2; ++p) {
      for (int k = 0; k < 4; ++k) {
        int e = p * 4 + k;
        k_conv<<<1024, 256, 0, stream>>>(xpad, wtb + (size_t)e * 147456, bufs[k],
                                         partials + (size_t)e * 16384);
      }
      k_redstats<<<4, 512, 0, stream>>>(partials + (size_t)p * 4 * 16384,
                                        stats + p * 4 * 128, 128);
      int flags = (p > 0 ? 1 : 0) | (p == 1 ? 2 : 0);
      k_merge<4><<<8192, 256, 0, stream>>>(bufs[0], bufs[1], bufs[2], bufs[3], stats,
                                           expert_g, expert_b, wts, merged, xpad,
                                           partials2, p * 4, flags);
    }
  } else {
    for (int p = 0; p < 4; ++p) {
      for (int k = 0; k < 2; ++k) {
        int e = p * 2 + k;
        k_conv<<<1024, 256, 0, stream>>>(xpad, wtb + (size_t)e * 147456, bufs[k],
                                         partials + (size_t)e * 16384);
      }
      k_redstats<<<2, 512, 0, stream>>>(partials + (size_t)p * 2 * 16384,
                                        stats + p * 2 * 128, 128);
      int flags = (p > 0 ? 1 : 0) | (p == 3 ? 2 : 0);
      k_merge<2><<<8192, 256, 0, stream>>>(bufs[0], bufs[1], bufs[0], bufs[1], stats,
                                           expert_g, expert_b, wts, merged, xpad,
                                           partials2, p * 2, flags);
    }
  }
  k_redstats2<<<128, 256, 0, stream>>>(partials2, stats + 8 * 128);
  k_ypass<<<8192, 256, 0, stream>>>(merged, xpad, stats + 8 * 128, merge_g, merge_b, gamma);
  k_conv<<<1024, 256, 0, stream>>>(xpad, wtb + 1179648ull, bufs[0],
                                   partials + (size_t)8 * 16384);
  k_redstats<<<1, 512, 0, stream>>>(partials + (size_t)8 * 16384, stats + 9 * 128, 128);
  k_final<<<2048, 256, 0, stream>>>((const __hip_bfloat16*)bufs[0], stats + 9 * 128,
                                    post_g, post_b, (float*)d_out);
}

// Round 6
// 469.311 us; speedup vs baseline: 4.4502x; 1.3812x over previous
//
#include <hip/hip_runtime.h>
#include <hip/hip_bf16.h>

// ---------------------------------------------------------------------------
// PCELayer. Expert convs as implicit GEMM on fp8 MFMA (gamma=0.01 damps the
// expert-path quantization error ~100x); post conv stays bf16.
// k_conv8: 64-ci permuted rows -> one ds_read_b128 feeds two K=32 fp8 MFMAs;
// 6 stage-units (m97 dbuf), 96 MFMA/wave/unit. Merge: fp8 decode + 1-FMA GN
// + rcp-approx silu.
// ---------------------------------------------------------------------------

typedef __attribute__((ext_vector_type(8))) short bf16x8;
typedef __attribute__((ext_vector_type(4))) float f32x4;
typedef __attribute__((ext_vector_type(2))) float f32x2;
typedef __attribute__((ext_vector_type(8))) unsigned short u16x8;
typedef __attribute__((ext_vector_type(4))) unsigned short u16x4;
typedef __attribute__((ext_vector_type(2))) unsigned int u32x2;
typedef __attribute__((ext_vector_type(2))) long lx2;

__device__ __forceinline__ float b2f(unsigned short u) {
  unsigned int v = ((unsigned int)u) << 16;
  return __builtin_bit_cast(float, v);
}
__device__ __forceinline__ unsigned short f2b(float f) {
  __hip_bfloat16 h = __float2bfloat16(f);
  return __builtin_bit_cast(unsigned short, h);
}
__device__ __forceinline__ float fsilu(float x) {  // rcp-approx silu
  float e = __expf(-x);
  return x * __builtin_amdgcn_rcpf(1.f + e);
}
__device__ __forceinline__ void gll16(const void* g, void* l) {
  __builtin_amdgcn_global_load_lds(
      (const __attribute__((address_space(1))) unsigned int*)g,
      (__attribute__((address_space(3))) unsigned int*)l, 16, 0, 0);
}
__device__ __forceinline__ unsigned char f2fp8(float v) {
  return (unsigned char)(__builtin_amdgcn_cvt_pk_fp8_f32(v, v, 0, false) & 0xff);
}

// ---- router: 64 patches x 8 experts -------------------------------------
__global__ void k_router(const float* __restrict__ rw, const float* __restrict__ rb,
                         float* __restrict__ wts) {
  int t = threadIdx.x;
  if (t >= 64) return;
  int py = t >> 3, px = t & 7;
  float cy = (py + 0.5f) / 8.f, cx = (px + 0.5f) / 8.f;
  const float PI = 3.14159265358979323846f;
  float f[16];
#pragma unroll
  for (int k = 0; k < 4; ++k) {
    float fr = (float)(1 << k) * PI;
    f[k]      = sinf(cy * fr);
    f[4 + k]  = cosf(cy * fr);
    f[8 + k]  = sinf(cx * fr);
    f[12 + k] = cosf(cx * fr);
  }
  float lg[8], mx = -1e30f;
#pragma unroll
  for (int e = 0; e < 8; ++e) {
    float a = rb[e];
#pragma unroll
    for (int k = 0; k < 16; ++k) a += f[k] * rw[k * 8 + e];
    lg[e] = a; mx = fmaxf(mx, a);
  }
  float s = 0.f;
#pragma unroll
  for (int e = 0; e < 8; ++e) { lg[e] = __expf(lg[e] - mx); s += lg[e]; }
  float inv = 1.f / s;
#pragma unroll
  for (int e = 0; e < 8; ++e) wts[t * 8 + e] = lg[e] * inv;
}

// ---- x (NCHW f32) -> padded NHWC bf16 [8][130][130][128] + fp8 permuted ---
__global__ void k_build_xpad(const float* __restrict__ x, __hip_bfloat16* __restrict__ xp,
                             unsigned char* __restrict__ xp8) {
  int bx = blockIdx.x;
  int wb = bx & 1, cib = (bx >> 1) & 1;
  int h = (bx >> 2) & 127, b = bx >> 9;
  int w0 = wb * 64, ci0 = cib * 64;
  __shared__ float t[64][65];
  int tid = threadIdx.x;
#pragma unroll
  for (int r = 0; r < 16; ++r) {
    int idx = r * 256 + tid;
    int i = idx >> 6, j = idx & 63;  // i: ci, j: w
    t[i][j] = x[(((size_t)b * 128 + ci0 + i) * 128 + h) * 128 + w0 + j];
  }
  __syncthreads();
  unsigned short* xpu = (unsigned short*)xp;
#pragma unroll
  for (int r = 0; r < 16; ++r) {
    int idx = r * 256 + tid;
    int j = idx >> 6, i = idx & 63;  // j: w, i: ci
    float v = t[i][j];
    size_t pixbase = ((size_t)b * 130 + h + 1) * 130 + (w0 + j + 1);
    xpu[pixbase * 128 + ci0 + i] = f2b(v);
    // fp8 permuted: ci -> cc2*64 + kg*16 + c*8 + jj
    int ci = ci0 + i;
    int cc2 = ci >> 6, cl = ci & 63;
    int p = ((cl >> 3) & 3) * 16 + ((cl >> 5) & 1) * 8 + (cl & 7);
    xp8[pixbase * 128 + cc2 * 64 + p] = f2fp8(v);
  }
}

// ---- post weights [co][ci][3][3] f32 -> [tap][co][ci] bf16 ----------------
__global__ void k_build_w(const float* __restrict__ src, __hip_bfloat16* __restrict__ dst,
                          int total) {
  int o = blockIdx.x * 256 + threadIdx.x;
  if (o >= total) return;
  int ci = o & 127, co = (o >> 7) & 127;
  int r = o >> 14; int tp = r % 9, e = r / 9;
  ((unsigned short*)dst)[o] =
      f2b(src[(((size_t)e * 128 + co) * 128 + ci) * 9 + tp]);
}

// ---- expert weights [e][co][ci][3][3] f32 -> [e][tap][co][128B perm] fp8 --
__global__ void k_build_w8(const float* __restrict__ src, unsigned char* __restrict__ dst,
                           int total) {
  int o = blockIdx.x * 256 + threadIdx.x;
  if (o >= total) return;
  int e = o / 147456;
  int r = o - e * 147456;
  int tp = r >> 14;
  int rem = r & 16383;
  int co = rem >> 7, rb = rem & 127;
  int cc2 = rb >> 6, pl = rb & 63;
  int kg = pl >> 4, c = (pl >> 3) & 1, j = pl & 7;
  int ci = cc2 * 64 + c * 32 + kg * 8 + j;
  dst[o] = f2fp8(src[(((size_t)e * 128 + co) * 128 + ci) * 9 + tp]);
}

// ---- expert conv3x3 fp8 implicit GEMM: 128 px x 128 cout, m97 dbuf --------
// 6 stage-units (cc2 x ky): A = 160px x 64ci (10.25KB) + B = 3 taps x 128co x
// 64ci (24.6KB); per unit 96 MFMA/wave (2 K-chunks per ds_read_b128).
__global__ __launch_bounds__(256, 2) void k_conv8(
    const unsigned char* __restrict__ xp8, const unsigned char* __restrict__ wt8,
    unsigned char* __restrict__ out8, float* __restrict__ partials) {
  __shared__ __align__(16) char smem[69632];  // 2 x (A 10240 + B 24576)
  const int bx0 = blockIdx.x;
  const int nid = (bx0 & 7) * 128 + (bx0 >> 3);  // XCD-chunk remap
  const int b = nid >> 7, h0 = nid & 127;
  const int tid = threadIdx.x;
  const int lane = tid & 63, wid = tid >> 6;
  const int wm = wid >> 1, wn = wid & 1;
  const int rl = lane & 15, kg = lane >> 4;

  int aoff[3][4];  // [kx][mb]
  int boff[3][4];  // [kx][nb]
#pragma unroll
  for (int mb = 0; mb < 4; ++mb) {
    int w = wm * 64 + mb * 16 + rl;
#pragma unroll
    for (int kx = 0; kx < 3; ++kx) {
      int px = w + kx;
      aoff[kx][mb] = (px * 4 + (kg ^ ((px >> 1) & 3))) * 16;
    }
  }
#pragma unroll
  for (int kx = 0; kx < 3; ++kx)
#pragma unroll
    for (int nb = 0; nb < 4; ++nb) {
      int co = wn * 64 + nb * 16 + rl;
      boff[kx][nb] = 10240 + ((kx * 128 + co) * 4 + (kg ^ ((co >> 1) & 3))) * 16;
    }

  f32x4 acc[4][4] = {};

#define STAGE8(bi, u)                                                         \
  {                                                                           \
    const int cc2_ = (u) / 3, ky_ = (u) - cc2_ * 3;                           \
    char* Al_ = smem + (bi) * 34816;                                          \
    char* Bl_ = Al_ + 10240;                                                  \
    const size_t arow_ = (size_t)(b * 130 + h0 + ky_) * 130;                  \
    _Pragma("unroll")                                                         \
    for (int it = 0; it < 3; ++it) {                                          \
      int s = it * 256 + tid;                                                 \
      if (it < 2 || tid < 128) {                                              \
        int px = s >> 2, q = s & 3;                                           \
        int qg = q ^ ((px >> 1) & 3);                                         \
        gll16(xp8 + (arow_ + px) * 128 + cc2_ * 64 + qg * 16, Al_ + s * 16);  \
      }                                                                       \
    }                                                                         \
    _Pragma("unroll")                                                         \
    for (int it = 0; it < 6; ++it) {                                          \
      int s = it * 256 + tid;                                                 \
      int t3 = s >> 9, rem = s & 511;                                         \
      int co = rem >> 2, q = rem & 3;                                         \
      int qg = q ^ ((co >> 1) & 3);                                           \
      gll16(wt8 + ((size_t)((ky_ * 3 + t3) * 128 + co)) * 128 + cc2_ * 64 +   \
                qg * 16,                                                      \
            Bl_ + s * 16);                                                    \
    }                                                                         \
  }

  STAGE8(0, 0);
  for (int u = 0; u < 6; ++u) {
    const int cur = u & 1;
    __syncthreads();
    if (u + 1 < 6) STAGE8(cur ^ 1, u + 1);
    char* Al = smem + cur * 34816;
#pragma unroll
    for (int kx = 0; kx < 3; ++kx) {
      lx2 av[4], bv[4];
#pragma unroll
      for (int mb = 0; mb < 4; ++mb) av[mb] = *(const lx2*)(Al + aoff[kx][mb]);
#pragma unroll
      for (int nb = 0; nb < 4; ++nb) bv[nb] = *(const lx2*)(Al + boff[kx][nb]);
#pragma unroll
      for (int c = 0; c < 2; ++c)
#pragma unroll
        for (int mb = 0; mb < 4; ++mb)
#pragma unroll
          for (int nb = 0; nb < 4; ++nb)
            acc[mb][nb] = __builtin_amdgcn_mfma_f32_16x16x32_fp8_fp8(
                bv[nb][c], av[mb][c], acc[mb][nb], 0, 0, 0);
    }
  }
#undef STAGE8

  // epilogue: pack fp8 + direct 4B stores; per-block GN partials
  float sv[4] = {0, 0, 0, 0}, qv[4] = {0, 0, 0, 0};
#pragma unroll
  for (int mb = 0; mb < 4; ++mb) {
    int w = wm * 64 + mb * 16 + rl;
    size_t base = (((size_t)b * 128 + h0) * 128 + w) * 128;
#pragma unroll
    for (int nb = 0; nb < 4; ++nb) {
      int co0 = wn * 64 + nb * 16 + kg * 4;
      f32x4 v = acc[mb][nb];
#pragma unroll
      for (int j = 0; j < 4; ++j) { sv[nb] += v[j]; qv[nb] += v[j] * v[j]; }
      int pk = __builtin_amdgcn_cvt_pk_fp8_f32(v[0], v[1], 0, false);
      pk = __builtin_amdgcn_cvt_pk_fp8_f32(v[2], v[3], pk, true);
      *(int*)(out8 + base + co0) = pk;
    }
  }
  __syncthreads();
  float* sg = (float*)smem;
  if (tid < 16) sg[tid] = 0.f;
  __syncthreads();
#pragma unroll
  for (int nb = 0; nb < 4; ++nb) {
    float a = sv[nb], q = qv[nb];
#pragma unroll
    for (int o = 32; o > 0; o >>= 1) { a += __shfl_down(a, o); q += __shfl_down(q, o); }
    if (lane == 0) {
      int g = wn * 4 + nb;
      atomicAdd(&sg[g * 2 + 0], a);
      atomicAdd(&sg[g * 2 + 1], q);
    }
  }
  __syncthreads();
  if (tid < 16) partials[(size_t)nid * 16 + tid] = sg[tid];
}

// ---- post conv3x3 bf16 (R5 structure, unchanged) --------------------------
__global__ __launch_bounds__(256, 2) void k_conv(
    const unsigned short* __restrict__ xpu, const unsigned short* __restrict__ wtu,
    unsigned short* __restrict__ outu, float* __restrict__ partials) {
  __shared__ __align__(16) char smem[69632];
  const int bx0 = blockIdx.x;
  const int nid = (bx0 & 7) * 128 + (bx0 >> 3);
  const int b = nid >> 7, h0 = nid & 127;
  const int tid = threadIdx.x;
  const int lane = tid & 63, wid = tid >> 6;
  const int wm = wid >> 1, wn = wid & 1;
  const int rl = lane & 15, kg = lane >> 4;

  int aoff[3][4];
  int boff[3][4];
#pragma unroll
  for (int mb = 0; mb < 4; ++mb) {
    int w = wm * 64 + mb * 16 + rl;
#pragma unroll
    for (int kx = 0; kx < 3; ++kx) {
      int px = w + kx;
      aoff[kx][mb] = (px * 4 + (kg ^ ((px >> 1) & 3))) * 16;
    }
  }
#pragma unroll
  for (int kx = 0; kx < 3; ++kx)
#pragma unroll
    for (int nb = 0; nb < 4; ++nb) {
      int co = wn * 64 + nb * 16 + rl;
      boff[kx][nb] = 10240 + ((kx * 128 + co) * 4 + (kg ^ ((co >> 1) & 3))) * 16;
    }

  f32x4 acc[4][4] = {};

#define STAGE(bi, u)                                                          \
  {                                                                           \
    const int cc_ = (u) / 3, ky_ = (u) - cc_ * 3;                             \
    char* Al_ = smem + (bi) * 34816;                                          \
    char* Bl_ = Al_ + 10240;                                                  \
    const size_t arow_ = (size_t)(b * 130 + h0 + ky_) * 130;                  \
    _Pragma("unroll")                                                         \
    for (int it = 0; it < 3; ++it) {                                          \
      int s = it * 256 + tid;                                                 \
      if (it < 2 || tid < 128) {                                              \
        int px = s >> 2, q = s & 3;                                           \
        int qg = q ^ ((px >> 1) & 3);                                         \
        gll16(xpu + (arow_ + px) * 128 + cc_ * 32 + qg * 8, Al_ + s * 16);    \
      }                                                                       \
    }                                                                         \
    _Pragma("unroll")                                                         \
    for (int it = 0; it < 6; ++it) {                                          \
      int s = it * 256 + tid;                                                 \
      int t3 = s >> 9, rem = s & 511;                                         \
      int co = rem >> 2, q = rem & 3;                                         \
      int qg = q ^ ((co >> 1) & 3);                                           \
      gll16(wtu + ((size_t)((ky_ * 3 + t3) * 128 + co)) * 128 + cc_ * 32 +    \
                qg * 8,                                                       \
            Bl_ + s * 16);                                                    \
    }                                                                         \
  }

  STAGE(0, 0);
  for (int u = 0; u < 12; ++u) {
    const int cur = u & 1;
    __syncthreads();
    if (u + 1 < 12) STAGE(cur ^ 1, u + 1);
    char* Al = smem + cur * 34816;
#pragma unroll
    for (int kx = 0; kx < 3; ++kx) {
      bf16x8 aF[4], bF[4];
#pragma unroll
      for (int mb = 0; mb < 4; ++mb) aF[mb] = *(const bf16x8*)(Al + aoff[kx][mb]);
#pragma unroll
      for (int nb = 0; nb < 4; ++nb) bF[nb] = *(const bf16x8*)(Al + boff[kx][nb]);
#pragma unroll
      for (int mb = 0; mb < 4; ++mb)
#pragma unroll
        for (int nb = 0; nb < 4; ++nb)
          acc[mb][nb] = __builtin_amdgcn_mfma_f32_16x16x32_bf16(
              bF[nb], aF[mb], acc[mb][nb], 0, 0, 0);
    }
  }
#undef STAGE

  float sv[4] = {0, 0, 0, 0}, qv[4] = {0, 0, 0, 0};
#pragma unroll
  for (int mb = 0; mb < 4; ++mb) {
    int w = wm * 64 + mb * 16 + rl;
    size_t base = (((size_t)b * 128 + h0) * 128 + w) * 128;
#pragma unroll
    for (int nb = 0; nb < 4; ++nb) {
      int co0 = wn * 64 + nb * 16 + kg * 4;
      u16x4 pk;
#pragma unroll
      for (int j = 0; j < 4; ++j) {
        float v = acc[mb][nb][j];
        pk[j] = f2b(v);
        sv[nb] += v; qv[nb] += v * v;
      }
      *(u16x4*)(outu + base + co0) = pk;
    }
  }
  __syncthreads();
  float* sg = (float*)smem;
  if (tid < 16) sg[tid] = 0.f;
  __syncthreads();
#pragma unroll
  for (int nb = 0; nb < 4; ++nb) {
    float a = sv[nb], q = qv[nb];
#pragma unroll
    for (int o = 32; o > 0; o >>= 1) { a += __shfl_down(a, o); q += __shfl_down(q, o); }
    if (lane == 0) {
      int g = wn * 4 + nb;
      atomicAdd(&sg[g * 2 + 0], a);
      atomicAdd(&sg[g * 2 + 1], q);
    }
  }
  __syncthreads();
  if (tid < 16) partials[(size_t)nid * 16 + tid] = sg[tid];
}

// ---- reduce per-block partials -> stats; blockIdx = set ------------------
__global__ void k_redstats(const float* __restrict__ partials, float* __restrict__ stats,
                           int nper) {
  int set = blockIdx.x;
  const float* p = partials + (size_t)set * 8 * nper * 16;
  float* st = stats + set * 128;
  int t = threadIdx.x;
  int o = t >> 2, j = t & 3;
  int b = o >> 4, slot = o & 15;
  int chunk = nper >> 2;
  float s = 0.f;
  for (int i = j * chunk; i < (j + 1) * chunk; ++i)
    s += p[((size_t)b * nper + i) * 16 + slot];
  s += __shfl_xor(s, 1);
  s += __shfl_xor(s, 2);
  if (j == 0) st[o] = s;
}

// ---- reduce merge partials (8192 x 16) -> stats2 --------------------------
__global__ void k_redstats2(const float* __restrict__ p2, float* __restrict__ st) {
  int o = blockIdx.x;  // 0..127
  int b = o >> 4, slot = o & 15;
  float s = 0.f;
  for (int i = threadIdx.x; i < 1024; i += 256)
    s += p2[((size_t)b * 1024 + i) * 16 + slot];
#pragma unroll
  for (int off = 32; off > 0; off >>= 1) s += __shfl_down(s, off);
  __shared__ float wsm[4];
  int lane = threadIdx.x & 63, wv = threadIdx.x >> 6;
  if (lane == 0) wsm[wv] = s;
  __syncthreads();
  if (threadIdx.x == 0) st[o] = wsm[0] + wsm[1] + wsm[2] + wsm[3];
}

// ---- merge NEXP fp8 experts ------------------------------------------------
// flags: bit0 = accumulate; bit1 = last pass (add x, write merge-GN partials)
template <int NEXP>
__global__ void k_merge(const unsigned char* __restrict__ c0,
                        const unsigned char* __restrict__ c1,
                        const unsigned char* __restrict__ c2,
                        const unsigned char* __restrict__ c3,
                        const float* __restrict__ st, const float* __restrict__ eg,
                        const float* __restrict__ eb, const float* __restrict__ wts,
                        unsigned short* __restrict__ merged,
                        const unsigned short* __restrict__ xp,
                        float* __restrict__ partials2, int e0, int flags) {
  __shared__ float sg[16];
  int tid = threadIdx.x;
  if (tid < 16) sg[tid] = 0.f;
  __syncthreads();
  size_t idx = ((size_t)blockIdx.x * 256 + tid) * 8;
  int co0 = (int)(idx & 127);
  size_t pix = idx >> 7;
  int w = (int)(pix & 127), h = (int)((pix >> 7) & 127), b = (int)(pix >> 14);
  int g = co0 >> 4;
  const float cnt = 16.f * 128.f * 128.f;
  int patch = (h >> 4) * 8 + (w >> 4);
  const unsigned char* cs[4] = {c0, c1, c2, c3};
  float a[8] = {0, 0, 0, 0, 0, 0, 0, 0};
#pragma unroll
  for (int k = 0; k < NEXP; ++k) {
    int e = e0 + k;
    float mean = st[e * 128 + (b * 8 + g) * 2] / cnt;
    float var = st[e * 128 + (b * 8 + g) * 2 + 1] / cnt - mean * mean;
    float rstd = rsqrtf(var + 1e-5f);
    float we = wts[patch * 8 + e];
    f32x4 g0 = *(const f32x4*)(eg + e * 128 + co0);
    f32x4 g1 = *(const f32x4*)(eg + e * 128 + co0 + 4);
    f32x4 b0 = *(const f32x4*)(eb + e * 128 + co0);
    f32x4 b1 = *(const f32x4*)(eb + e * 128 + co0 + 4);
    u32x2 cv = *(const u32x2*)(cs[k] + idx);
    f32x2 d0 = __builtin_amdgcn_cvt_pk_f32_fp8(cv[0], false);
    f32x2 d1 = __builtin_amdgcn_cvt_pk_f32_fp8(cv[0], true);
    f32x2 d2 = __builtin_amdgcn_cvt_pk_f32_fp8(cv[1], false);
    f32x2 d3 = __builtin_amdgcn_cvt_pk_f32_fp8(cv[1], true);
    float d[8] = {d0[0], d0[1], d1[0], d1[1], d2[0], d2[1], d3[0], d3[1]};
#pragma unroll
    for (int i = 0; i < 8; ++i) {
      float gi = (i < 4) ? g0[i] : g1[i - 4];
      float bi = (i < 4) ? b0[i] : b1[i - 4];
      float A = rstd * gi;
      float B = bi - mean * A;
      a[i] += we * fsilu(d[i] * A + B);
    }
  }
  if (flags & 1) {
    u16x8 mv = *(const u16x8*)(merged + idx);
#pragma unroll
    for (int i = 0; i < 8; ++i) a[i] += b2f(mv[i]);
  }
  u16x8 out;
  float s = 0.f, q = 0.f;
  if (flags & 2) {
    const unsigned short* xr =
        xp + (((size_t)b * 130 + h + 1) * 130 + (w + 1)) * 128 + co0;
    u16x8 xv = *(const u16x8*)xr;
#pragma unroll
    for (int i = 0; i < 8; ++i) {
      a[i] += b2f(xv[i]);
      out[i] = f2b(a[i]);
      float rv = b2f(out[i]);
      s += rv; q += rv * rv;
    }
  } else {
#pragma unroll
    for (int i = 0; i < 8; ++i) out[i] = f2b(a[i]);
  }
  *(u16x8*)(merged + idx) = out;
  if (flags & 2) {
    atomicAdd(&sg[g * 2 + 0], s);
    atomicAdd(&sg[g * 2 + 1], q);
    __syncthreads();
    if (tid < 16) partials2[(size_t)blockIdx.x * 16 + tid] = sg[tid];
  }
}

// ---- y = x + gamma*silu(gn(M)); write bf16 y into padded buffer (in place) -
__global__ void k_ypass(const unsigned short* __restrict__ merged,
                        unsigned short* __restrict__ xp,
                        const float* __restrict__ st, const float* __restrict__ mg,
                        const float* __restrict__ mbv, const float* __restrict__ gptr) {
  size_t idx = ((size_t)blockIdx.x * 256 + threadIdx.x) * 8;
  int co0 = (int)(idx & 127);
  size_t pix = idx >> 7;
  int w = (int)(pix & 127), h = (int)((pix >> 7) & 127), b = (int)(pix >> 14);
  int g = co0 >> 4;
  const float cnt = 16.f * 128.f * 128.f;
  float mean = st[(b * 8 + g) * 2] / cnt;
  float var = st[(b * 8 + g) * 2 + 1] / cnt - mean * mean;
  float rstd = rsqrtf(var + 1e-5f);
  float gm = gptr[0];
  unsigned short* xr = xp + (((size_t)b * 130 + h + 1) * 130 + (w + 1)) * 128 + co0;
  u16x8 xv = *(const u16x8*)xr;
  u16x8 mv = *(const u16x8*)(merged + idx);
  u16x8 yv;
#pragma unroll
  for (int i = 0; i < 8; ++i) {
    float xf = b2f(xv[i]);
    float M = b2f(mv[i]);
    float xn = (M - mean) * rstd * mg[co0 + i] + mbv[co0 + i];
    yv[i] = f2b(xf + gm * fsilu(xn));
  }
  *(u16x8*)xr = yv;
}

// ---- final: out = silu(gn3(conv3)), NHWC bf16 -> NCHW f32 via LDS transpose
__global__ void k_final(const __hip_bfloat16* __restrict__ conv, const float* __restrict__ st,
                        const float* __restrict__ pg, const float* __restrict__ pb,
                        float* __restrict__ out) {
  int bx = blockIdx.x;
  int wb = bx & 1, h = (bx >> 1) & 127, b = bx >> 8;
  int w0 = wb * 64;
  __shared__ float t[64][129];
  int tid = threadIdx.x;
  const float cnt = 16.f * 128.f * 128.f;
  const unsigned short* cu = (const unsigned short*)conv;
#pragma unroll
  for (int r = 0; r < 32; ++r) {
    int e2 = r * 256 + tid;
    int co = e2 & 127, wl = e2 >> 7;
    int g = co >> 4;
    float mean = st[(b * 8 + g) * 2] / cnt;
    float var = st[(b * 8 + g) * 2 + 1] / cnt - mean * mean;
    float rstd = rsqrtf(var + 1e-5f);
    float v = b2f(cu[(((size_t)b * 128 + h) * 128 + w0 + wl) * 128 + co]);
    float xn = (v - mean) * rstd * pg[co] + pb[co];
    t[wl][co] = fsilu(xn);
  }
  __syncthreads();
#pragma unroll
  for (int r = 0; r < 8; ++r) {
    int f = r * 256 + tid;
    int jb = f & 15, co = f >> 4;
    f32x4 o;
#pragma unroll
    for (int j = 0; j < 4; ++j) o[j] = t[jb * 4 + j][co];
    *(f32x4*)&out[(((size_t)b * 128 + co) * 128 + h) * 128 + w0 + jb * 4] = o;
  }
}

// ---------------------------------------------------------------------------
extern "C" void kernel_launch(void* const* d_in, const int* in_sizes, int n_in,
                              void* d_out, int out_size, void* d_ws, size_t ws_size,
                              hipStream_t stream) {
  const float* x        = (const float*)d_in[0];
  const float* expert_w = (const float*)d_in[1];
  const float* expert_g = (const float*)d_in[2];
  const float* expert_b = (const float*)d_in[3];
  const float* router_w = (const float*)d_in[4];
  const float* router_b = (const float*)d_in[5];
  const float* merge_g  = (const float*)d_in[6];
  const float* merge_b  = (const float*)d_in[7];
  const float* gamma    = (const float*)d_in[8];
  const float* post_w   = (const float*)d_in[9];
  const float* post_g   = (const float*)d_in[10];
  const float* post_b   = (const float*)d_in[11];

  char* ws = (char*)d_ws;
  float* wts            = (float*)(ws + 0);               // 2048
  float* stats          = (float*)(ws + 2048);            // 5120
  float* partials       = (float*)(ws + 8192);            // 655360
  float* partials2      = (float*)(ws + 663552);          // 524288
  unsigned short* wtbp  = (unsigned short*)(ws + 1187840);   // post bf16 294912
  unsigned char* wtb8   = (unsigned char*)(ws + 1482752);    // exp fp8 1179648
  unsigned short* xpad  = (unsigned short*)(ws + 2662400);   // 34611200 + 8192
  unsigned char* xpad8  = (unsigned char*)(ws + 37281792);   // 17305600 + 4096
  const size_t BUFS = 54591488ull;
  const size_t FB = 16777216ull;  // fp8 buf bytes
  const size_t NEED2 = BUFS + 2 * FB + 33554432ull;  // 121,700,352
  const size_t NEED4 = BUFS + 4 * FB + 33554432ull;  // 155,254,784
  int nbuf = (ws_size >= NEED4) ? 4 : 2;
  unsigned char* bufs[4];
  unsigned short* merged;
  bufs[0] = (unsigned char*)(ws + BUFS);
  bufs[1] = (unsigned char*)(ws + BUFS + FB);
  if (nbuf == 4) {
    bufs[2] = (unsigned char*)(ws + BUFS + 2 * FB);
    bufs[3] = (unsigned char*)(ws + BUFS + 3 * FB);
    merged  = (unsigned short*)(ws + BUFS + 4 * FB);
  } else {
    bufs[2] = bufs[0]; bufs[3] = bufs[1];
    merged  = (unsigned short*)(ws + BUFS + 2 * FB);
  }
  unsigned short* pbuf = (unsigned short*)(ws + BUFS);  // post conv bf16 out
  if (ws_size < NEED2) {  // graceful fallback, no corruption
    hipMemsetAsync(d_out, 0, (size_t)out_size * 4, stream);
    return;
  }

  // zero both padded xpads in one call (contiguous regions)
  hipMemsetAsync(xpad, 0, 34619392ull + 17309696ull, stream);
  k_router<<<1, 64, 0, stream>>>(router_w, router_b, wts);
  k_build_xpad<<<4096, 256, 0, stream>>>(x, (__hip_bfloat16*)xpad, xpad8);
  k_build_w<<<576, 256, 0, stream>>>(post_w, (__hip_bfloat16*)wtbp, 147456);
  k_build_w8<<<4608, 256, 0, stream>>>(expert_w, wtb8, 1179648);

  if (nbuf == 4) {
    for (int p = 0; p < 2; ++p) {
      for (int k = 0; k < 4; ++k) {
        int e = p * 4 + k;
        k_conv8<<<1024, 256, 0, stream>>>(xpad8, wtb8 + (size_t)e * 147456, bufs[k],
                                          partials + (size_t)e * 16384);
      }
      k_redstats<<<4, 512, 0, stream>>>(partials + (size_t)p * 4 * 16384,
                                        stats + p * 4 * 128, 128);
      int flags = (p > 0 ? 1 : 0) | (p == 1 ? 2 : 0);
      k_merge<4><<<8192, 256, 0, stream>>>(bufs[0], bufs[1], bufs[2], bufs[3], stats,
                                           expert_g, expert_b, wts, merged, xpad,
                                           partials2, p * 4, flags);
    }
  } else {
    for (int p = 0; p < 4; ++p) {
      for (int k = 0; k < 2; ++k) {
        int e = p * 2 + k;
        k_conv8<<<1024, 256, 0, stream>>>(xpad8, wtb8 + (size_t)e * 147456, bufs[k],
                                          partials + (size_t)e * 16384);
      }
      k_redstats<<<2, 512, 0, stream>>>(partials + (size_t)p * 2 * 16384,
                                        stats + p * 2 * 128, 128);
      int flags = (p > 0 ? 1 : 0) | (p == 3 ? 2 : 0);
      k_merge<2><<<8192, 256, 0, stream>>>(bufs[0], bufs[1], bufs[0], bufs[1], stats,
                                           expert_g, expert_b, wts, merged, xpad,
                                           partials2, p * 2, flags);
    }
  }
  k_redstats2<<<128, 256, 0, stream>>>(partials2, stats + 8 * 128);
  k_ypass<<<8192, 256, 0, stream>>>(merged, xpad, stats + 8 * 128, merge_g, merge_b, gamma);
  k_conv<<<1024, 256, 0, stream>>>(xpad, wtbp, pbuf, partials + (size_t)8 * 16384);
  k_redstats<<<1, 512, 0, stream>>>(partials + (size_t)8 * 16384, stats + 9 * 128, 128);
  k_final<<<2048, 256, 0, stream>>>((const __hip_bfloat16*)pbuf, stats + 9 * 128,
                                    post_g, post_b, (float*)d_out);
}